// Round 15
// baseline (202.458 us; speedup 1.0000x reference)
//
#include <hip/hip_runtime.h>

constexpr int N_NODES  = 100000;
constexpr int N_EDGES  = 3200000;
constexpr int N_GRAPHS = 64;

constexpr int BSHIFT   = 8;                              // 256 nodes per bin
constexpr int NBINS    = (N_NODES + 255) >> BSHIFT;      // 391
constexpr int BIN_CAP  = 9216;                           // mean 8184, +11 sigma
constexpr int SRC_BITS = 17;                             // 100000 < 2^17
constexpr int SRC_MASK = (1 << SRC_BITS) - 1;

constexpr int NB_BIN = 500;                              // ~2 blocks/CU
constexpr int EPB    = N_EDGES / NB_BIN;                 // 6400 (exact)
constexpr int EPT    = (EPB + 1023) / 1024;              // 7

typedef float v4f __attribute__((ext_vector_type(4)));

// ================= CSR build: block-local LDS counting sort =================

__global__ __launch_bounds__(1024) void bin_kernel(
        const int* __restrict__ src, const int* __restrict__ dst,
        int* __restrict__ bin_cur, int* __restrict__ binned) {
    __shared__ int pk[EPB];                 // packed (ln<<17)|src, load order
    __shared__ unsigned short bn[EPB];      // bin id, load order
    __shared__ unsigned short ord[EPB];     // sorted pos -> load index
    __shared__ int hist[NBINS];
    __shared__ int lexcl[NBINS];
    __shared__ int lofs[NBINS];
    __shared__ int gofs[NBINS];
    __shared__ int s512[512];
    int tid = threadIdx.x;
    int e0 = blockIdx.x * EPB;
    for (int i = tid; i < NBINS; i += 1024) hist[i] = 0;
    __syncthreads();
#pragma unroll
    for (int k = 0; k < EPT; ++k) {
        int i = tid + k * 1024;
        if (i < EPB) {
            int d = __builtin_nontemporal_load(&dst[e0 + i]);
            int s = __builtin_nontemporal_load(&src[e0 + i]);
            int b = d >> BSHIFT;
            pk[i] = ((d & 255) << SRC_BITS) | s;
            bn[i] = (unsigned short)b;
            atomicAdd(&hist[b], 1);
        }
    }
    __syncthreads();
    if (tid < 512) s512[tid] = (tid < NBINS) ? hist[tid] : 0;
    __syncthreads();
    for (int o = 1; o < 512; o <<= 1) {
        int x = 0;
        if (tid < 512 && tid >= o) x = s512[tid - o];
        __syncthreads();
        if (tid < 512) s512[tid] += x;
        __syncthreads();
    }
    if (tid < NBINS) {
        int h = hist[tid];
        int excl = s512[tid] - h;
        lexcl[tid] = excl;
        lofs[tid]  = excl;
        gofs[tid]  = h ? atomicAdd(&bin_cur[tid], h) : 0;
    }
    __syncthreads();
#pragma unroll
    for (int k = 0; k < EPT; ++k) {
        int i = tid + k * 1024;
        if (i < EPB) {
            int r = atomicAdd(&lofs[bn[i]], 1);
            ord[r] = (unsigned short)i;
        }
    }
    __syncthreads();
#pragma unroll
    for (int k = 0; k < EPT; ++k) {
        int i = tid + k * 1024;
        if (i < EPB) {
            int j = ord[i];
            int b = bn[j];
            int pos = gofs[b] + (i - lexcl[b]);
            if (pos < BIN_CAP)
                __builtin_nontemporal_store(pk[j], &binned[(size_t)b * BIN_CAP + pos]);
        }
    }
}

__global__ void binscan_kernel(const int* __restrict__ bin_cur, int* __restrict__ bin_base,
                               int* __restrict__ rowptr) {
    __shared__ int s[512];
    int t = threadIdx.x;
    int v = (t < NBINS) ? bin_cur[t] : 0;
    s[t] = v;
    __syncthreads();
    for (int o = 1; o < 512; o <<= 1) {
        int x = (t >= o) ? s[t - o] : 0;
        __syncthreads();
        s[t] += x;
        __syncthreads();
    }
    if (t < NBINS) bin_base[t] = s[t] - v;
    if (t == 0) rowptr[N_NODES] = N_EDGES;
}

// One block per 256-node bin. Single LDS-atomic pass captures per-edge rank;
// also emits dis[] AND xs[] (pre1 fused: xs = x * dis).
__global__ __launch_bounds__(1024) void csrbuild_kernel(
        const int* __restrict__ binned, const int* __restrict__ bin_cur,
        const int* __restrict__ bin_base, const float* __restrict__ x,
        int* __restrict__ rowptr, float* __restrict__ dis,
        float* __restrict__ xs, int* __restrict__ csr) {
    __shared__ int cnt[256];
    __shared__ int lofs[256];
    __shared__ int s[256];
    int b = blockIdx.x;
    int t = threadIdx.x;
    int size  = min(bin_cur[b], BIN_CAP);
    int gbase = bin_base[b];
    const int* bp = binned + (size_t)b * BIN_CAP;
    if (t < 256) cnt[t] = 0;
    __syncthreads();
    int pc[9];                                   // 9*1024 >= BIN_CAP
    unsigned char rk[9];                         // rank within row (max deg ~66)
#pragma unroll
    for (int k = 0; k < 9; ++k) {
        int i = t + k * 1024;
        pc[k] = -1; rk[k] = 0;
        if (i < size) {
            pc[k] = __builtin_nontemporal_load(&bp[i]);
            rk[k] = (unsigned char)atomicAdd(&cnt[pc[k] >> SRC_BITS], 1);
        }
    }
    __syncthreads();
    if (t < 256) {
        int n = (b << BSHIFT) + t;
        int deg = cnt[t];
        if (n < N_NODES) {
            float di = 1.0f / sqrtf((float)deg + 1.0f);  // +1 self loop
            dis[n] = di;
            float4 v;                                    // fused pre1
            v.x = __builtin_nontemporal_load(&x[(size_t)n * 3 + 0]) * di;
            v.y = __builtin_nontemporal_load(&x[(size_t)n * 3 + 1]) * di;
            v.z = __builtin_nontemporal_load(&x[(size_t)n * 3 + 2]) * di;
            v.w = 0.f;
            *reinterpret_cast<float4*>(&xs[(size_t)n * 4]) = v;
        }
        s[t] = deg;
    }
    __syncthreads();
    for (int o = 1; o < 256; o <<= 1) {
        int xum = 0;
        if (t < 256 && t >= o) xum = s[t - o];
        __syncthreads();
        if (t < 256) s[t] += xum;
        __syncthreads();
    }
    if (t < 256) {
        int n = (b << BSHIFT) + t;
        int excl = s[t] - cnt[t];
        if (n < N_NODES) rowptr[n] = gbase + excl;
        lofs[t] = excl;
    }
    __syncthreads();
#pragma unroll
    for (int k = 0; k < 9; ++k) {
        int i = t + k * 1024;
        if (i < size) {
            int p = pc[k];
            int ln = p >> SRC_BITS;
            csr[gbase + lofs[ln] + rk[k]] = p & SRC_MASK;
        }
    }
}

// ================= per-layer kernels =================

// Row-parallel gather: 16 lanes/node = 4 sublanes (features) x 4 quarters.
template<int F, bool ADD_B, bool RELU>
__global__ __launch_bounds__(256) void gather_kernel(
        const float* __restrict__ in, const int* __restrict__ rowptr,
        const int* __restrict__ csr, const float* __restrict__ dis,
        const float* __restrict__ b, float* __restrict__ out) {
    constexpr int VPL = F / 4;          // features per sublane
    constexpr int NPB = 256 / 16;       // 16 nodes per block
    int tid  = threadIdx.x;
    int sub  = tid & 3;                 // feature sublane
    int qtr  = (tid >> 2) & 3;          // edge-range quarter
    int n    = blockIdx.x * NPB + (tid >> 4);
    if (n >= N_NODES) return;           // never taken: 6250*16 == N exactly
    int beg = rowptr[n], end = rowptr[n + 1];
    int len = end - beg;
    int kb = beg + ((len * qtr) >> 2);
    int ke = beg + ((len * (qtr + 1)) >> 2);
    const float* ip = in + (size_t)sub * VPL;
    float a0[VPL], a1[VPL], a2[VPL], a3[VPL];
#pragma unroll
    for (int j = 0; j < VPL; ++j) { a0[j] = 0.f; a1[j] = 0.f; a2[j] = 0.f; a3[j] = 0.f; }
    if (qtr == 0) {
#pragma unroll
        for (int j = 0; j < VPL; ++j) a0[j] = ip[(size_t)n * F + j];  // self loop
    }
    int k = kb;
    for (; k + 7 < ke; k += 8) {
        int s0 = __builtin_nontemporal_load(&csr[k + 0]);
        int s1 = __builtin_nontemporal_load(&csr[k + 1]);
        int s2 = __builtin_nontemporal_load(&csr[k + 2]);
        int s3 = __builtin_nontemporal_load(&csr[k + 3]);
        int s4 = __builtin_nontemporal_load(&csr[k + 4]);
        int s5 = __builtin_nontemporal_load(&csr[k + 5]);
        int s6 = __builtin_nontemporal_load(&csr[k + 6]);
        int s7 = __builtin_nontemporal_load(&csr[k + 7]);
        const float* r0 = &ip[(size_t)s0 * F];
        const float* r1 = &ip[(size_t)s1 * F];
        const float* r2 = &ip[(size_t)s2 * F];
        const float* r3 = &ip[(size_t)s3 * F];
        const float* r4 = &ip[(size_t)s4 * F];
        const float* r5 = &ip[(size_t)s5 * F];
        const float* r6 = &ip[(size_t)s6 * F];
        const float* r7 = &ip[(size_t)s7 * F];
#pragma unroll
        for (int j = 0; j < VPL; ++j) a0[j] += r0[j];
#pragma unroll
        for (int j = 0; j < VPL; ++j) a1[j] += r1[j];
#pragma unroll
        for (int j = 0; j < VPL; ++j) a2[j] += r2[j];
#pragma unroll
        for (int j = 0; j < VPL; ++j) a3[j] += r3[j];
#pragma unroll
        for (int j = 0; j < VPL; ++j) a0[j] += r4[j];
#pragma unroll
        for (int j = 0; j < VPL; ++j) a1[j] += r5[j];
#pragma unroll
        for (int j = 0; j < VPL; ++j) a2[j] += r6[j];
#pragma unroll
        for (int j = 0; j < VPL; ++j) a3[j] += r7[j];
    }
    if (k + 3 < ke) {
        int s0 = __builtin_nontemporal_load(&csr[k + 0]);
        int s1 = __builtin_nontemporal_load(&csr[k + 1]);
        int s2 = __builtin_nontemporal_load(&csr[k + 2]);
        int s3 = __builtin_nontemporal_load(&csr[k + 3]);
        const float* r0 = &ip[(size_t)s0 * F];
        const float* r1 = &ip[(size_t)s1 * F];
        const float* r2 = &ip[(size_t)s2 * F];
        const float* r3 = &ip[(size_t)s3 * F];
#pragma unroll
        for (int j = 0; j < VPL; ++j) a0[j] += r0[j];
#pragma unroll
        for (int j = 0; j < VPL; ++j) a1[j] += r1[j];
#pragma unroll
        for (int j = 0; j < VPL; ++j) a2[j] += r2[j];
#pragma unroll
        for (int j = 0; j < VPL; ++j) a3[j] += r3[j];
        k += 4;
    }
    for (; k < ke; ++k) {
        int s0 = __builtin_nontemporal_load(&csr[k]);
        const float* r0 = &ip[(size_t)s0 * F];
#pragma unroll
        for (int j = 0; j < VPL; ++j) a0[j] += r0[j];
    }
    float v[VPL];
#pragma unroll
    for (int j = 0; j < VPL; ++j) v[j] = (a0[j] + a1[j]) + (a2[j] + a3[j]);
#pragma unroll
    for (int j = 0; j < VPL; ++j) v[j] += __shfl_xor(v[j], 4);
#pragma unroll
    for (int j = 0; j < VPL; ++j) v[j] += __shfl_xor(v[j], 8);
    if (qtr == 0) {
        float d = dis[n];
#pragma unroll
        for (int j = 0; j < VPL; ++j) {
            float w = v[j] * d;
            if (ADD_B) w += b[sub * VPL + j];
            if (RELU) w = fmaxf(w, 0.f);
            __builtin_nontemporal_store(w, &out[(size_t)n * F + sub * VPL + j]);
        }
    }
}

// Layer-2 gather (F=16, single-phase, full 8-unroll) + fused W3 epilogue:
// writes g8 = (relu(h2)@W3)*dis directly. w3s stored transposed (bank-safe).
__global__ __launch_bounds__(256) void gather16w3_kernel(
        const float* __restrict__ in, const int* __restrict__ rowptr,
        const int* __restrict__ csr, const float* __restrict__ dis,
        const float* __restrict__ b2, const float* __restrict__ W3,
        float* __restrict__ g8) {
    __shared__ float w3s[128];                   // transposed: w3s[o*16+f]
    int tid = threadIdx.x;
    if (tid < 128) {
        int f = tid >> 3, o = tid & 7;
        w3s[o * 16 + f] = W3[tid];
    }
    __syncthreads();
    constexpr int F = 16, VPL = 4;
    int sub = tid & 3, qtr = (tid >> 2) & 3;
    int n = blockIdx.x * 16 + (tid >> 4);
    int beg = rowptr[n], end = rowptr[n + 1];
    int len = end - beg;
    int kb = beg + ((len * qtr) >> 2);
    int ke = beg + ((len * (qtr + 1)) >> 2);
    const float* ip = in + (size_t)sub * VPL;
    float a0[4], a1[4], a2[4], a3[4];
#pragma unroll
    for (int j = 0; j < 4; ++j) { a1[j] = 0.f; a2[j] = 0.f; a3[j] = 0.f; }
#pragma unroll
    for (int j = 0; j < 4; ++j) a0[j] = (qtr == 0) ? ip[(size_t)n * F + j] : 0.f;  // self
    int k = kb;
    for (; k + 7 < ke; k += 8) {
        int s0 = __builtin_nontemporal_load(&csr[k + 0]);
        int s1 = __builtin_nontemporal_load(&csr[k + 1]);
        int s2 = __builtin_nontemporal_load(&csr[k + 2]);
        int s3 = __builtin_nontemporal_load(&csr[k + 3]);
        int s4 = __builtin_nontemporal_load(&csr[k + 4]);
        int s5 = __builtin_nontemporal_load(&csr[k + 5]);
        int s6 = __builtin_nontemporal_load(&csr[k + 6]);
        int s7 = __builtin_nontemporal_load(&csr[k + 7]);
        const float* r0 = &ip[(size_t)s0 * F];
        const float* r1 = &ip[(size_t)s1 * F];
        const float* r2 = &ip[(size_t)s2 * F];
        const float* r3 = &ip[(size_t)s3 * F];
        const float* r4 = &ip[(size_t)s4 * F];
        const float* r5 = &ip[(size_t)s5 * F];
        const float* r6 = &ip[(size_t)s6 * F];
        const float* r7 = &ip[(size_t)s7 * F];
#pragma unroll
        for (int j = 0; j < 4; ++j) a0[j] += r0[j];
#pragma unroll
        for (int j = 0; j < 4; ++j) a1[j] += r1[j];
#pragma unroll
        for (int j = 0; j < 4; ++j) a2[j] += r2[j];
#pragma unroll
        for (int j = 0; j < 4; ++j) a3[j] += r3[j];
#pragma unroll
        for (int j = 0; j < 4; ++j) a0[j] += r4[j];
#pragma unroll
        for (int j = 0; j < 4; ++j) a1[j] += r5[j];
#pragma unroll
        for (int j = 0; j < 4; ++j) a2[j] += r6[j];
#pragma unroll
        for (int j = 0; j < 4; ++j) a3[j] += r7[j];
    }
    if (k + 3 < ke) {
        int s0 = __builtin_nontemporal_load(&csr[k + 0]);
        int s1 = __builtin_nontemporal_load(&csr[k + 1]);
        int s2 = __builtin_nontemporal_load(&csr[k + 2]);
        int s3 = __builtin_nontemporal_load(&csr[k + 3]);
        const float* r0 = &ip[(size_t)s0 * F];
        const float* r1 = &ip[(size_t)s1 * F];
        const float* r2 = &ip[(size_t)s2 * F];
        const float* r3 = &ip[(size_t)s3 * F];
#pragma unroll
        for (int j = 0; j < 4; ++j) a0[j] += r0[j];
#pragma unroll
        for (int j = 0; j < 4; ++j) a1[j] += r1[j];
#pragma unroll
        for (int j = 0; j < 4; ++j) a2[j] += r2[j];
#pragma unroll
        for (int j = 0; j < 4; ++j) a3[j] += r3[j];
        k += 4;
    }
    for (; k < ke; ++k) {
        int s0 = __builtin_nontemporal_load(&csr[k]);
        const float* r0 = &ip[(size_t)s0 * F];
#pragma unroll
        for (int j = 0; j < 4; ++j) a0[j] += r0[j];
    }
    float d = dis[n];
    float w[4];
#pragma unroll
    for (int j = 0; j < 4; ++j) {
        float v = (a0[j] + a1[j]) + (a2[j] + a3[j]);
        v += __shfl_xor(v, 4);
        v += __shfl_xor(v, 8);                    // all lanes hold full sum
        w[j] = fmaxf(fmaf(v, d, b2[sub * 4 + j]), 0.f);   // h2 slice (relu'd)
    }
    float p[8];
#pragma unroll
    for (int o = 0; o < 8; ++o) {
        float s = 0.f;
#pragma unroll
        for (int j = 0; j < 4; ++j) s = fmaf(w[j], w3s[o * 16 + sub * 4 + j], s);
        s += __shfl_xor(s, 1);
        s += __shfl_xor(s, 2);                    // sum over sublanes
        p[o] = s;
    }
    if (qtr == 0) {
        __builtin_nontemporal_store(p[sub * 2 + 0] * d, &g8[(size_t)n * 8 + sub * 2 + 0]);
        __builtin_nontemporal_store(p[sub * 2 + 1] * d, &g8[(size_t)n * 8 + sub * 2 + 1]);
    }
}

// Fused: m -> relu(m@W1+b1) -> (@W2)*dis -> g   (h1 never hits memory)
__global__ __launch_bounds__(256) void linfuse_kernel(
        const float* __restrict__ m, const float* __restrict__ W1,
        const float* __restrict__ b1, const float* __restrict__ W2,
        const float* __restrict__ dis, float* __restrict__ g) {
    __shared__ float w2s[512];
    __shared__ float w1s[96];
    __shared__ float b1s[32];
    int tid = threadIdx.x;
    for (int j = tid; j < 512; j += 256) w2s[j] = W2[j];
    if (tid < 96) w1s[tid] = W1[tid];
    if (tid < 32) b1s[tid] = b1[tid];
    __syncthreads();
    int i = blockIdx.x * blockDim.x + tid;
    if (i >= N_NODES) return;
    float4 mv = *reinterpret_cast<const float4*>(&m[(size_t)i * 4]);
    float h[32];
#pragma unroll
    for (int f = 0; f < 32; ++f) {
        float s = b1s[f];
        s = fmaf(mv.x, w1s[f], s);
        s = fmaf(mv.y, w1s[32 + f], s);
        s = fmaf(mv.z, w1s[64 + f], s);
        h[f] = fmaxf(s, 0.f);
    }
    float d = dis[i];
#pragma unroll
    for (int o = 0; o < 16; ++o) {
        float s = 0.f;
#pragma unroll
        for (int f = 0; f < 32; ++f) s = fmaf(h[f], w2s[f * 16 + o], s);
        g[(size_t)i * 16 + o] = s * d;
    }
}

// ================= pooling + final linear =================

// Grid-stride over nodes: 64 blocks, LDS init/flush amortized.
__global__ __launch_bounds__(256) void pool_kernel(
        const float* __restrict__ h, const int* __restrict__ batch,
        float* __restrict__ pool) {
    __shared__ float lsum[N_GRAPHS * 8];
    __shared__ float lcnt[N_GRAPHS];
    int tid = threadIdx.x;
    for (int j = tid; j < N_GRAPHS * 8; j += 256) lsum[j] = 0.f;
    if (tid < N_GRAPHS) lcnt[tid] = 0.f;
    __syncthreads();
    for (int i = blockIdx.x * 256 + tid; i < N_NODES; i += gridDim.x * 256) {
        int gm = batch[i];
        const float4* hp = reinterpret_cast<const float4*>(&h[(size_t)i * 8]);
        float4 a = hp[0], bq = hp[1];
        atomicAdd(&lsum[gm * 8 + 0], a.x);
        atomicAdd(&lsum[gm * 8 + 1], a.y);
        atomicAdd(&lsum[gm * 8 + 2], a.z);
        atomicAdd(&lsum[gm * 8 + 3], a.w);
        atomicAdd(&lsum[gm * 8 + 4], bq.x);
        atomicAdd(&lsum[gm * 8 + 5], bq.y);
        atomicAdd(&lsum[gm * 8 + 6], bq.z);
        atomicAdd(&lsum[gm * 8 + 7], bq.w);
        atomicAdd(&lcnt[gm], 1.0f);
    }
    __syncthreads();
    for (int idx = tid; idx < N_GRAPHS * 9; idx += 256) {
        int gm = idx / 9, j = idx % 9;
        if (lcnt[gm] != 0.f) {
            if (j < 8) atomicAdd(&pool[gm * 8 + j], lsum[gm * 8 + j]);
            else       atomicAdd(&pool[512 + gm], lcnt[gm]);
        }
    }
}

__global__ void final_kernel(const float* __restrict__ pool, const float* __restrict__ Wf,
                             const float* __restrict__ bf, float* __restrict__ out) {
    int t = threadIdx.x;
    if (t >= N_GRAPHS * 3) return;
    int gm = t / 3, c = t % 3;
    float cnt = fmaxf(pool[512 + gm], 1.0f);
    float s = 0.f;
#pragma unroll
    for (int f = 0; f < 8; ++f) s = fmaf(pool[gm * 8 + f] / cnt, Wf[f * 3 + c], s);
    out[t] = s + bf[c];
}

// ================= launch =================

extern "C" void kernel_launch(void* const* d_in, const int* in_sizes, int n_in,
                              void* d_out, int out_size, void* d_ws, size_t ws_size,
                              hipStream_t stream) {
    const float* x     = (const float*)d_in[0];
    const int*   ei    = (const int*)d_in[1];
    const int*   batch = (const int*)d_in[2];
    const float* W1 = (const float*)d_in[3];
    const float* b1 = (const float*)d_in[4];
    const float* W2 = (const float*)d_in[5];
    const float* b2 = (const float*)d_in[6];
    const float* W3 = (const float*)d_in[7];
    const float* b3 = (const float*)d_in[8];
    const float* Wf = (const float*)d_in[9];
    const float* bf = (const float*)d_in[10];

    const int* src = ei;              // edge_index[0] = message sources
    const int* dst = ei + N_EDGES;    // edge_index[1] = aggregation targets

    const int N = N_NODES;

    // workspace; binned (36N ints) aliases act[0,36N) floats.
    // act liveness (units of N floats):
    //   csrbuild: reads binned[0,36N), writes xs[36,40)   (disjoint!)
    //   L1: xs[36,40) -> m[4,8) (binned dead) -> [linfuse] -> g[8,24)
    //   L2+W3: g[8,24) -> g8[24,32)
    //   L3: g8[24,32) -> h3[0,8) -> pool
    int*   bin_cur  = (int*)d_ws;                         // NBINS
    int*   bin_base = bin_cur + NBINS;                    // NBINS
    int*   rowptr   = bin_base + NBINS;                   // N+2
    float* dis      = (float*)(rowptr + N + 2);           // N
    int*   csr      = (int*)(dis + N);                    // E
    float* act      = (float*)(csr + N_EDGES);            // 40N floats
    int*   binned   = (int*)act;                          // 36N ints
    float* m    = act + (size_t)4  * N;                   // 4N
    float* g    = act + (size_t)8  * N;                   // 16N
    float* g8   = act + (size_t)24 * N;                   // 8N
    float* xs   = act + (size_t)36 * N;                   // 4N (outside binned!)
    float* h3   = act;                                    // 8N [0,8) (binned dead at L3)
    float* pool = act + (size_t)40 * N;                   // 576

    const int B = 256;
    const int NB_N = (N + B - 1) / B;     // 391
    const int NB_G = N / 16;              // 6250 (exact)

    hipMemsetAsync(bin_cur, 0, NBINS * sizeof(int), stream);
    hipMemsetAsync(pool, 0, N_GRAPHS * 9 * sizeof(float), stream);

    // CSR build (csrbuild also emits dis and xs = x*dis — pre1 fused)
    bin_kernel<<<NB_BIN, 1024, 0, stream>>>(src, dst, bin_cur, binned);
    binscan_kernel<<<1, 512, 0, stream>>>(bin_cur, bin_base, rowptr);
    csrbuild_kernel<<<NBINS, 1024, 0, stream>>>(binned, bin_cur, bin_base, x,
                                                rowptr, dis, xs, csr);

    // Layer 1: 4-wide gather, then fused (W1+relu)+(W2·dis)
    gather_kernel<4, false, false><<<NB_G, B, 0, stream>>>(xs, rowptr, csr, dis, b1, m);
    linfuse_kernel<<<NB_N, B, 0, stream>>>(m, W1, b1, W2, dis, g);

    // Layer 2: 16-wide row-parallel gather + fused W3 epilogue -> g8
    gather16w3_kernel<<<NB_G, B, 0, stream>>>(g, rowptr, csr, dis, b2, W3, g8);

    // Layer 3: 8-wide row-parallel gather (+b3, relu)
    gather_kernel<8, true, true><<<NB_G, B, 0, stream>>>(g8, rowptr, csr, dis, b3, h3);

    // Pool + final linear
    pool_kernel<<<64, B, 0, stream>>>(h3, batch, pool);
    final_kernel<<<1, 256, 0, stream>>>(pool, Wf, bf, (float*)d_out);
}

// Round 16
// 187.487 us; speedup vs baseline: 1.0799x; 1.0799x over previous
//
#include <hip/hip_runtime.h>

constexpr int N_NODES  = 100000;
constexpr int N_EDGES  = 3200000;
constexpr int N_GRAPHS = 64;

constexpr int BSHIFT   = 8;                              // 256 nodes per bin
constexpr int NBINS    = (N_NODES + 255) >> BSHIFT;      // 391
constexpr int BIN_CAP  = 9216;                           // mean 8184, +11 sigma
constexpr int SRC_BITS = 17;                             // 100000 < 2^17
constexpr int SRC_MASK = (1 << SRC_BITS) - 1;

constexpr int NB_BIN = 500;                              // ~2 blocks/CU
constexpr int EPB    = N_EDGES / NB_BIN;                 // 6400 (exact)
constexpr int EPT    = (EPB + 1023) / 1024;              // 7

typedef float v4f __attribute__((ext_vector_type(4)));

// ================= CSR build: block-local LDS counting sort =================

__global__ __launch_bounds__(1024) void bin_kernel(
        const int* __restrict__ src, const int* __restrict__ dst,
        int* __restrict__ bin_cur, int* __restrict__ binned) {
    __shared__ int pk[EPB];                 // packed (ln<<17)|src, load order
    __shared__ unsigned short bn[EPB];      // bin id, load order
    __shared__ unsigned short ord[EPB];     // sorted pos -> load index
    __shared__ int hist[NBINS];
    __shared__ int lexcl[NBINS];
    __shared__ int lofs[NBINS];
    __shared__ int gofs[NBINS];
    __shared__ int s512[512];
    int tid = threadIdx.x;
    int e0 = blockIdx.x * EPB;
    for (int i = tid; i < NBINS; i += 1024) hist[i] = 0;
    __syncthreads();
#pragma unroll
    for (int k = 0; k < EPT; ++k) {
        int i = tid + k * 1024;
        if (i < EPB) {
            int d = __builtin_nontemporal_load(&dst[e0 + i]);
            int s = __builtin_nontemporal_load(&src[e0 + i]);
            int b = d >> BSHIFT;
            pk[i] = ((d & 255) << SRC_BITS) | s;
            bn[i] = (unsigned short)b;
            atomicAdd(&hist[b], 1);
        }
    }
    __syncthreads();
    if (tid < 512) s512[tid] = (tid < NBINS) ? hist[tid] : 0;
    __syncthreads();
    for (int o = 1; o < 512; o <<= 1) {
        int x = 0;
        if (tid < 512 && tid >= o) x = s512[tid - o];
        __syncthreads();
        if (tid < 512) s512[tid] += x;
        __syncthreads();
    }
    if (tid < NBINS) {
        int h = hist[tid];
        int excl = s512[tid] - h;
        lexcl[tid] = excl;
        lofs[tid]  = excl;
        gofs[tid]  = h ? atomicAdd(&bin_cur[tid], h) : 0;
    }
    __syncthreads();
#pragma unroll
    for (int k = 0; k < EPT; ++k) {
        int i = tid + k * 1024;
        if (i < EPB) {
            int r = atomicAdd(&lofs[bn[i]], 1);
            ord[r] = (unsigned short)i;
        }
    }
    __syncthreads();
#pragma unroll
    for (int k = 0; k < EPT; ++k) {
        int i = tid + k * 1024;
        if (i < EPB) {
            int j = ord[i];
            int b = bn[j];
            int pos = gofs[b] + (i - lexcl[b]);
            if (pos < BIN_CAP)
                __builtin_nontemporal_store(pk[j], &binned[(size_t)b * BIN_CAP + pos]);
        }
    }
}

__global__ void binscan_kernel(const int* __restrict__ bin_cur, int* __restrict__ bin_base,
                               int* __restrict__ rowptr) {
    __shared__ int s[512];
    int t = threadIdx.x;
    int v = (t < NBINS) ? bin_cur[t] : 0;
    s[t] = v;
    __syncthreads();
    for (int o = 1; o < 512; o <<= 1) {
        int x = (t >= o) ? s[t - o] : 0;
        __syncthreads();
        s[t] += x;
        __syncthreads();
    }
    if (t < NBINS) bin_base[t] = s[t] - v;
    if (t == 0) rowptr[N_NODES] = N_EDGES;
}

__global__ __launch_bounds__(1024) void csrbuild_kernel(
        const int* __restrict__ binned, const int* __restrict__ bin_cur,
        const int* __restrict__ bin_base, int* __restrict__ rowptr,
        float* __restrict__ dis, int* __restrict__ csr) {
    __shared__ int cnt[256];
    __shared__ int lofs[256];
    __shared__ int s[256];
    int b = blockIdx.x;
    int t = threadIdx.x;
    int size  = min(bin_cur[b], BIN_CAP);
    int gbase = bin_base[b];
    const int* bp = binned + (size_t)b * BIN_CAP;
    if (t < 256) cnt[t] = 0;
    __syncthreads();
    int pc[9];                                   // 9*1024 >= BIN_CAP
#pragma unroll
    for (int k = 0; k < 9; ++k) {
        int i = t + k * 1024;
        pc[k] = (i < size) ? __builtin_nontemporal_load(&bp[i]) : -1;
        if (i < size) atomicAdd(&cnt[pc[k] >> SRC_BITS], 1);
    }
    __syncthreads();
    if (t < 256) {
        int n = (b << BSHIFT) + t;
        int deg = cnt[t];
        if (n < N_NODES) dis[n] = 1.0f / sqrtf((float)deg + 1.0f);  // +1 self loop
        s[t] = deg;
    }
    __syncthreads();
    for (int o = 1; o < 256; o <<= 1) {
        int x = 0;
        if (t < 256 && t >= o) x = s[t - o];
        __syncthreads();
        if (t < 256) s[t] += x;
        __syncthreads();
    }
    if (t < 256) {
        int n = (b << BSHIFT) + t;
        int excl = s[t] - cnt[t];
        if (n < N_NODES) rowptr[n] = gbase + excl;
        lofs[t] = excl;
        cnt[t] = 0;
    }
    __syncthreads();
#pragma unroll
    for (int k = 0; k < 9; ++k) {
        int i = t + k * 1024;
        if (i < size) {
            int p = pc[k];
            int ln = p >> SRC_BITS;
            int r = atomicAdd(&cnt[ln], 1);
            csr[gbase + lofs[ln] + r] = p & SRC_MASK;
        }
    }
}

// ================= per-layer kernels =================

__global__ void pre1_kernel(const float* __restrict__ x, const float* __restrict__ dis,
                            float* __restrict__ xs) {
    int i = blockIdx.x * blockDim.x + threadIdx.x;
    if (i >= N_NODES) return;
    float d = dis[i];
    float4 v;
    v.x = __builtin_nontemporal_load(&x[(size_t)i * 3 + 0]) * d;
    v.y = __builtin_nontemporal_load(&x[(size_t)i * 3 + 1]) * d;
    v.z = __builtin_nontemporal_load(&x[(size_t)i * 3 + 2]) * d;
    v.w = 0.f;
    *reinterpret_cast<float4*>(&xs[(size_t)i * 4]) = v;
}

// Row-parallel gather: 16 lanes/node = 4 sublanes (features) x 4 quarters.
template<int F, bool ADD_B, bool RELU>
__global__ __launch_bounds__(256) void gather_kernel(
        const float* __restrict__ in, const int* __restrict__ rowptr,
        const int* __restrict__ csr, const float* __restrict__ dis,
        const float* __restrict__ b, float* __restrict__ out) {
    constexpr int VPL = F / 4;          // features per sublane
    constexpr int NPB = 256 / 16;       // 16 nodes per block
    int tid  = threadIdx.x;
    int sub  = tid & 3;                 // feature sublane
    int qtr  = (tid >> 2) & 3;          // edge-range quarter
    int n    = blockIdx.x * NPB + (tid >> 4);
    if (n >= N_NODES) return;           // never taken: 6250*16 == N exactly
    int beg = rowptr[n], end = rowptr[n + 1];
    int len = end - beg;
    int kb = beg + ((len * qtr) >> 2);
    int ke = beg + ((len * (qtr + 1)) >> 2);
    const float* ip = in + (size_t)sub * VPL;
    float a0[VPL], a1[VPL], a2[VPL], a3[VPL];
#pragma unroll
    for (int j = 0; j < VPL; ++j) { a0[j] = 0.f; a1[j] = 0.f; a2[j] = 0.f; a3[j] = 0.f; }
    if (qtr == 0) {
#pragma unroll
        for (int j = 0; j < VPL; ++j) a0[j] = ip[(size_t)n * F + j];  // self loop
    }
    int k = kb;
    for (; k + 7 < ke; k += 8) {
        int s0 = __builtin_nontemporal_load(&csr[k + 0]);
        int s1 = __builtin_nontemporal_load(&csr[k + 1]);
        int s2 = __builtin_nontemporal_load(&csr[k + 2]);
        int s3 = __builtin_nontemporal_load(&csr[k + 3]);
        int s4 = __builtin_nontemporal_load(&csr[k + 4]);
        int s5 = __builtin_nontemporal_load(&csr[k + 5]);
        int s6 = __builtin_nontemporal_load(&csr[k + 6]);
        int s7 = __builtin_nontemporal_load(&csr[k + 7]);
        const float* r0 = &ip[(size_t)s0 * F];
        const float* r1 = &ip[(size_t)s1 * F];
        const float* r2 = &ip[(size_t)s2 * F];
        const float* r3 = &ip[(size_t)s3 * F];
        const float* r4 = &ip[(size_t)s4 * F];
        const float* r5 = &ip[(size_t)s5 * F];
        const float* r6 = &ip[(size_t)s6 * F];
        const float* r7 = &ip[(size_t)s7 * F];
#pragma unroll
        for (int j = 0; j < VPL; ++j) a0[j] += r0[j];
#pragma unroll
        for (int j = 0; j < VPL; ++j) a1[j] += r1[j];
#pragma unroll
        for (int j = 0; j < VPL; ++j) a2[j] += r2[j];
#pragma unroll
        for (int j = 0; j < VPL; ++j) a3[j] += r3[j];
#pragma unroll
        for (int j = 0; j < VPL; ++j) a0[j] += r4[j];
#pragma unroll
        for (int j = 0; j < VPL; ++j) a1[j] += r5[j];
#pragma unroll
        for (int j = 0; j < VPL; ++j) a2[j] += r6[j];
#pragma unroll
        for (int j = 0; j < VPL; ++j) a3[j] += r7[j];
    }
    if (k + 3 < ke) {
        int s0 = __builtin_nontemporal_load(&csr[k + 0]);
        int s1 = __builtin_nontemporal_load(&csr[k + 1]);
        int s2 = __builtin_nontemporal_load(&csr[k + 2]);
        int s3 = __builtin_nontemporal_load(&csr[k + 3]);
        const float* r0 = &ip[(size_t)s0 * F];
        const float* r1 = &ip[(size_t)s1 * F];
        const float* r2 = &ip[(size_t)s2 * F];
        const float* r3 = &ip[(size_t)s3 * F];
#pragma unroll
        for (int j = 0; j < VPL; ++j) a0[j] += r0[j];
#pragma unroll
        for (int j = 0; j < VPL; ++j) a1[j] += r1[j];
#pragma unroll
        for (int j = 0; j < VPL; ++j) a2[j] += r2[j];
#pragma unroll
        for (int j = 0; j < VPL; ++j) a3[j] += r3[j];
        k += 4;
    }
    for (; k < ke; ++k) {
        int s0 = __builtin_nontemporal_load(&csr[k]);
        const float* r0 = &ip[(size_t)s0 * F];
#pragma unroll
        for (int j = 0; j < VPL; ++j) a0[j] += r0[j];
    }
    float v[VPL];
#pragma unroll
    for (int j = 0; j < VPL; ++j) v[j] = (a0[j] + a1[j]) + (a2[j] + a3[j]);
#pragma unroll
    for (int j = 0; j < VPL; ++j) v[j] += __shfl_xor(v[j], 4);
#pragma unroll
    for (int j = 0; j < VPL; ++j) v[j] += __shfl_xor(v[j], 8);
    if (qtr == 0) {
        float d = dis[n];
#pragma unroll
        for (int j = 0; j < VPL; ++j) {
            float w = v[j] * d;
            if (ADD_B) w += b[sub * VPL + j];
            if (RELU) w = fmaxf(w, 0.f);
            __builtin_nontemporal_store(w, &out[(size_t)n * F + sub * VPL + j]);
        }
    }
}

// Layer-2 gather (F=16, single-phase, full 8-unroll) + fused W3 epilogue:
// writes g8 = (relu(h2)@W3)*dis directly. w3s stored transposed (bank-safe,
// verified: SQ_LDS_BANK_CONFLICT 800K -> 75K in round 14).
__global__ __launch_bounds__(256) void gather16w3_kernel(
        const float* __restrict__ in, const int* __restrict__ rowptr,
        const int* __restrict__ csr, const float* __restrict__ dis,
        const float* __restrict__ b2, const float* __restrict__ W3,
        float* __restrict__ g8) {
    __shared__ float w3s[128];                   // transposed: w3s[o*16+f]
    int tid = threadIdx.x;
    if (tid < 128) {
        int f = tid >> 3, o = tid & 7;
        w3s[o * 16 + f] = W3[tid];
    }
    __syncthreads();
    constexpr int F = 16, VPL = 4;
    int sub = tid & 3, qtr = (tid >> 2) & 3;
    int n = blockIdx.x * 16 + (tid >> 4);
    int beg = rowptr[n], end = rowptr[n + 1];
    int len = end - beg;
    int kb = beg + ((len * qtr) >> 2);
    int ke = beg + ((len * (qtr + 1)) >> 2);
    const float* ip = in + (size_t)sub * VPL;
    float a0[4], a1[4], a2[4], a3[4];
#pragma unroll
    for (int j = 0; j < 4; ++j) { a1[j] = 0.f; a2[j] = 0.f; a3[j] = 0.f; }
#pragma unroll
    for (int j = 0; j < 4; ++j) a0[j] = (qtr == 0) ? ip[(size_t)n * F + j] : 0.f;  // self
    int k = kb;
    for (; k + 7 < ke; k += 8) {
        int s0 = __builtin_nontemporal_load(&csr[k + 0]);
        int s1 = __builtin_nontemporal_load(&csr[k + 1]);
        int s2 = __builtin_nontemporal_load(&csr[k + 2]);
        int s3 = __builtin_nontemporal_load(&csr[k + 3]);
        int s4 = __builtin_nontemporal_load(&csr[k + 4]);
        int s5 = __builtin_nontemporal_load(&csr[k + 5]);
        int s6 = __builtin_nontemporal_load(&csr[k + 6]);
        int s7 = __builtin_nontemporal_load(&csr[k + 7]);
        const float* r0 = &ip[(size_t)s0 * F];
        const float* r1 = &ip[(size_t)s1 * F];
        const float* r2 = &ip[(size_t)s2 * F];
        const float* r3 = &ip[(size_t)s3 * F];
        const float* r4 = &ip[(size_t)s4 * F];
        const float* r5 = &ip[(size_t)s5 * F];
        const float* r6 = &ip[(size_t)s6 * F];
        const float* r7 = &ip[(size_t)s7 * F];
#pragma unroll
        for (int j = 0; j < 4; ++j) a0[j] += r0[j];
#pragma unroll
        for (int j = 0; j < 4; ++j) a1[j] += r1[j];
#pragma unroll
        for (int j = 0; j < 4; ++j) a2[j] += r2[j];
#pragma unroll
        for (int j = 0; j < 4; ++j) a3[j] += r3[j];
#pragma unroll
        for (int j = 0; j < 4; ++j) a0[j] += r4[j];
#pragma unroll
        for (int j = 0; j < 4; ++j) a1[j] += r5[j];
#pragma unroll
        for (int j = 0; j < 4; ++j) a2[j] += r6[j];
#pragma unroll
        for (int j = 0; j < 4; ++j) a3[j] += r7[j];
    }
    if (k + 3 < ke) {
        int s0 = __builtin_nontemporal_load(&csr[k + 0]);
        int s1 = __builtin_nontemporal_load(&csr[k + 1]);
        int s2 = __builtin_nontemporal_load(&csr[k + 2]);
        int s3 = __builtin_nontemporal_load(&csr[k + 3]);
        const float* r0 = &ip[(size_t)s0 * F];
        const float* r1 = &ip[(size_t)s1 * F];
        const float* r2 = &ip[(size_t)s2 * F];
        const float* r3 = &ip[(size_t)s3 * F];
#pragma unroll
        for (int j = 0; j < 4; ++j) a0[j] += r0[j];
#pragma unroll
        for (int j = 0; j < 4; ++j) a1[j] += r1[j];
#pragma unroll
        for (int j = 0; j < 4; ++j) a2[j] += r2[j];
#pragma unroll
        for (int j = 0; j < 4; ++j) a3[j] += r3[j];
        k += 4;
    }
    for (; k < ke; ++k) {
        int s0 = __builtin_nontemporal_load(&csr[k]);
        const float* r0 = &ip[(size_t)s0 * F];
#pragma unroll
        for (int j = 0; j < 4; ++j) a0[j] += r0[j];
    }
    float d = dis[n];
    float w[4];
#pragma unroll
    for (int j = 0; j < 4; ++j) {
        float v = (a0[j] + a1[j]) + (a2[j] + a3[j]);
        v += __shfl_xor(v, 4);
        v += __shfl_xor(v, 8);                    // all lanes hold full sum
        w[j] = fmaxf(fmaf(v, d, b2[sub * 4 + j]), 0.f);   // h2 slice (relu'd)
    }
    float p[8];
#pragma unroll
    for (int o = 0; o < 8; ++o) {
        float s = 0.f;
#pragma unroll
        for (int j = 0; j < 4; ++j) s = fmaf(w[j], w3s[o * 16 + sub * 4 + j], s);
        s += __shfl_xor(s, 1);
        s += __shfl_xor(s, 2);                    // sum over sublanes
        p[o] = s;
    }
    if (qtr == 0) {
        __builtin_nontemporal_store(p[sub * 2 + 0] * d, &g8[(size_t)n * 8 + sub * 2 + 0]);
        __builtin_nontemporal_store(p[sub * 2 + 1] * d, &g8[(size_t)n * 8 + sub * 2 + 1]);
    }
}

// Fused: m -> relu(m@W1+b1) -> (@W2)*dis -> g   (h1 never hits memory)
__global__ __launch_bounds__(256) void linfuse_kernel(
        const float* __restrict__ m, const float* __restrict__ W1,
        const float* __restrict__ b1, const float* __restrict__ W2,
        const float* __restrict__ dis, float* __restrict__ g) {
    __shared__ float w2s[512];
    __shared__ float w1s[96];
    __shared__ float b1s[32];
    int tid = threadIdx.x;
    for (int j = tid; j < 512; j += 256) w2s[j] = W2[j];
    if (tid < 96) w1s[tid] = W1[tid];
    if (tid < 32) b1s[tid] = b1[tid];
    __syncthreads();
    int i = blockIdx.x * blockDim.x + tid;
    if (i >= N_NODES) return;
    float4 mv = *reinterpret_cast<const float4*>(&m[(size_t)i * 4]);
    float h[32];
#pragma unroll
    for (int f = 0; f < 32; ++f) {
        float s = b1s[f];
        s = fmaf(mv.x, w1s[f], s);
        s = fmaf(mv.y, w1s[32 + f], s);
        s = fmaf(mv.z, w1s[64 + f], s);
        h[f] = fmaxf(s, 0.f);
    }
    float d = dis[i];
#pragma unroll
    for (int o = 0; o < 16; ++o) {
        float s = 0.f;
#pragma unroll
        for (int f = 0; f < 32; ++f) s = fmaf(h[f], w2s[f * 16 + o], s);
        g[(size_t)i * 16 + o] = s * d;
    }
}

// ================= pooling + final linear =================

__global__ void pool_kernel(const float* __restrict__ h, const int* __restrict__ batch,
                            float* __restrict__ pool) {
    __shared__ float lsum[N_GRAPHS * 8];
    __shared__ float lcnt[N_GRAPHS];
    int tid = threadIdx.x;
    for (int j = tid; j < N_GRAPHS * 8; j += blockDim.x) lsum[j] = 0.f;
    for (int j = tid; j < N_GRAPHS; j += blockDim.x) lcnt[j] = 0.f;
    __syncthreads();
    int i = blockIdx.x * blockDim.x + tid;
    if (i < N_NODES) {
        int gm = batch[i];
        const float4* hp = reinterpret_cast<const float4*>(&h[(size_t)i * 8]);
        float4 a = hp[0], bq = hp[1];
        atomicAdd(&lsum[gm * 8 + 0], a.x);
        atomicAdd(&lsum[gm * 8 + 1], a.y);
        atomicAdd(&lsum[gm * 8 + 2], a.z);
        atomicAdd(&lsum[gm * 8 + 3], a.w);
        atomicAdd(&lsum[gm * 8 + 4], bq.x);
        atomicAdd(&lsum[gm * 8 + 5], bq.y);
        atomicAdd(&lsum[gm * 8 + 6], bq.z);
        atomicAdd(&lsum[gm * 8 + 7], bq.w);
        atomicAdd(&lcnt[gm], 1.0f);
    }
    __syncthreads();
    for (int idx = tid; idx < N_GRAPHS * 9; idx += blockDim.x) {
        int gm = idx / 9, j = idx % 9;
        if (lcnt[gm] != 0.f) {
            if (j < 8) atomicAdd(&pool[gm * 8 + j], lsum[gm * 8 + j]);
            else       atomicAdd(&pool[512 + gm], lcnt[gm]);
        }
    }
}

__global__ void final_kernel(const float* __restrict__ pool, const float* __restrict__ Wf,
                             const float* __restrict__ bf, float* __restrict__ out) {
    int t = threadIdx.x;
    if (t >= N_GRAPHS * 3) return;
    int gm = t / 3, c = t % 3;
    float cnt = fmaxf(pool[512 + gm], 1.0f);
    float s = 0.f;
#pragma unroll
    for (int f = 0; f < 8; ++f) s = fmaf(pool[gm * 8 + f] / cnt, Wf[f * 3 + c], s);
    out[t] = s + bf[c];
}

// ================= launch =================

extern "C" void kernel_launch(void* const* d_in, const int* in_sizes, int n_in,
                              void* d_out, int out_size, void* d_ws, size_t ws_size,
                              hipStream_t stream) {
    const float* x     = (const float*)d_in[0];
    const int*   ei    = (const int*)d_in[1];
    const int*   batch = (const int*)d_in[2];
    const float* W1 = (const float*)d_in[3];
    const float* b1 = (const float*)d_in[4];
    const float* W2 = (const float*)d_in[5];
    const float* b2 = (const float*)d_in[6];
    const float* W3 = (const float*)d_in[7];
    const float* b3 = (const float*)d_in[8];
    const float* Wf = (const float*)d_in[9];
    const float* bf = (const float*)d_in[10];

    const int* src = ei;              // edge_index[0] = message sources
    const int* dst = ei + N_EDGES;    // edge_index[1] = aggregation targets

    const int N = N_NODES;

    // workspace; binned (36N ints) aliases the activation region (36N floats)
    // act liveness (units of N floats):
    //   L1: xs[0,4) -> m[4,8) -> [linfuse] -> g[8,24)
    //   L2+W3: g[8,24) -> g8[24,32)   (disjoint)
    //   L3: g8[24,32) -> h3[0,8)      (disjoint) -> pool
    int*   bin_cur  = (int*)d_ws;                         // NBINS
    int*   bin_base = bin_cur + NBINS;                    // NBINS
    int*   rowptr   = bin_base + NBINS;                   // N+2
    float* dis      = (float*)(rowptr + N + 2);           // N
    int*   csr      = (int*)(dis + N);                    // E
    float* act      = (float*)(csr + N_EDGES);            // 36N floats
    int*   binned   = (int*)act;                          // 36N ints
    float* xs   = act;                                    // 4N
    float* m    = act + (size_t)4  * N;                   // 4N
    float* g    = act + (size_t)8  * N;                   // 16N
    float* g8   = act + (size_t)24 * N;                   // 8N
    float* h3   = act;                                    // 8N [0,8) (xs,m dead at L3)
    float* pool = act + (size_t)36 * N;                   // 576

    const int B = 256;
    const int NB_N = (N + B - 1) / B;     // 391
    const int NB_G = N / 16;              // 6250 (exact)

    hipMemsetAsync(bin_cur, 0, NBINS * sizeof(int), stream);
    hipMemsetAsync(pool, 0, N_GRAPHS * 9 * sizeof(float), stream);

    // CSR build
    bin_kernel<<<NB_BIN, 1024, 0, stream>>>(src, dst, bin_cur, binned);
    binscan_kernel<<<1, 512, 0, stream>>>(bin_cur, bin_base, rowptr);
    csrbuild_kernel<<<NBINS, 1024, 0, stream>>>(binned, bin_cur, bin_base, rowptr, dis, csr);

    // Layer 1: aggregate padded 3-dim input, then fused (W1+relu)+(W2·dis)
    pre1_kernel<<<NB_N, B, 0, stream>>>(x, dis, xs);
    gather_kernel<4, false, false><<<NB_G, B, 0, stream>>>(xs, rowptr, csr, dis, b1, m);
    linfuse_kernel<<<NB_N, B, 0, stream>>>(m, W1, b1, W2, dis, g);

    // Layer 2: 16-wide row-parallel gather + fused W3 epilogue -> g8
    gather16w3_kernel<<<NB_G, B, 0, stream>>>(g, rowptr, csr, dis, b2, W3, g8);

    // Layer 3: 8-wide row-parallel gather (+b3, relu)
    gather_kernel<8, true, true><<<NB_G, B, 0, stream>>>(g8, rowptr, csr, dis, b3, h3);

    // Pool + final linear
    pool_kernel<<<NB_N, B, 0, stream>>>(h3, batch, pool);
    final_kernel<<<1, 256, 0, stream>>>(pool, Wf, bf, (float*)d_out);
}

// Round 17
// 175.479 us; speedup vs baseline: 1.1537x; 1.0684x over previous
//
#include <hip/hip_runtime.h>

constexpr int N_NODES  = 100000;
constexpr int N_EDGES  = 3200000;
constexpr int N_GRAPHS = 64;

constexpr int BSHIFT   = 8;                              // 256 nodes per bin
constexpr int NBINS    = (N_NODES + 255) >> BSHIFT;      // 391
constexpr int BIN_CAP  = 9216;                           // mean 8184, +11 sigma
constexpr int SRC_BITS = 17;                             // 100000 < 2^17
constexpr int SRC_MASK = (1 << SRC_BITS) - 1;

constexpr int NB_BIN = 500;                              // ~2 blocks/CU
constexpr int EPB    = N_EDGES / NB_BIN;                 // 6400 (exact)
constexpr int EPT    = (EPB + 1023) / 1024;              // 7

typedef float    v4f __attribute__((ext_vector_type(4)));
typedef _Float16 h2t __attribute__((ext_vector_type(2)));
typedef _Float16 h4t __attribute__((ext_vector_type(4)));

// ================= CSR build: block-local LDS counting sort =================

__global__ __launch_bounds__(1024) void bin_kernel(
        const int* __restrict__ src, const int* __restrict__ dst,
        int* __restrict__ bin_cur, int* __restrict__ binned) {
    __shared__ int pk[EPB];                 // packed (ln<<17)|src, load order
    __shared__ unsigned short bn[EPB];      // bin id, load order
    __shared__ unsigned short ord[EPB];     // sorted pos -> load index
    __shared__ int hist[NBINS];
    __shared__ int lexcl[NBINS];
    __shared__ int lofs[NBINS];
    __shared__ int gofs[NBINS];
    __shared__ int s512[512];
    int tid = threadIdx.x;
    int e0 = blockIdx.x * EPB;
    for (int i = tid; i < NBINS; i += 1024) hist[i] = 0;
    __syncthreads();
#pragma unroll
    for (int k = 0; k < EPT; ++k) {
        int i = tid + k * 1024;
        if (i < EPB) {
            int d = __builtin_nontemporal_load(&dst[e0 + i]);
            int s = __builtin_nontemporal_load(&src[e0 + i]);
            int b = d >> BSHIFT;
            pk[i] = ((d & 255) << SRC_BITS) | s;
            bn[i] = (unsigned short)b;
            atomicAdd(&hist[b], 1);
        }
    }
    __syncthreads();
    if (tid < 512) s512[tid] = (tid < NBINS) ? hist[tid] : 0;
    __syncthreads();
    for (int o = 1; o < 512; o <<= 1) {
        int x = 0;
        if (tid < 512 && tid >= o) x = s512[tid - o];
        __syncthreads();
        if (tid < 512) s512[tid] += x;
        __syncthreads();
    }
    if (tid < NBINS) {
        int h = hist[tid];
        int excl = s512[tid] - h;
        lexcl[tid] = excl;
        lofs[tid]  = excl;
        gofs[tid]  = h ? atomicAdd(&bin_cur[tid], h) : 0;
    }
    __syncthreads();
#pragma unroll
    for (int k = 0; k < EPT; ++k) {
        int i = tid + k * 1024;
        if (i < EPB) {
            int r = atomicAdd(&lofs[bn[i]], 1);
            ord[r] = (unsigned short)i;
        }
    }
    __syncthreads();
#pragma unroll
    for (int k = 0; k < EPT; ++k) {
        int i = tid + k * 1024;
        if (i < EPB) {
            int j = ord[i];
            int b = bn[j];
            int pos = gofs[b] + (i - lexcl[b]);
            if (pos < BIN_CAP)
                __builtin_nontemporal_store(pk[j], &binned[(size_t)b * BIN_CAP + pos]);
        }
    }
}

__global__ void binscan_kernel(const int* __restrict__ bin_cur, int* __restrict__ bin_base,
                               int* __restrict__ rowptr) {
    __shared__ int s[512];
    int t = threadIdx.x;
    int v = (t < NBINS) ? bin_cur[t] : 0;
    s[t] = v;
    __syncthreads();
    for (int o = 1; o < 512; o <<= 1) {
        int x = (t >= o) ? s[t - o] : 0;
        __syncthreads();
        s[t] += x;
        __syncthreads();
    }
    if (t < NBINS) bin_base[t] = s[t] - v;
    if (t == 0) rowptr[N_NODES] = N_EDGES;
}

__global__ __launch_bounds__(1024) void csrbuild_kernel(
        const int* __restrict__ binned, const int* __restrict__ bin_cur,
        const int* __restrict__ bin_base, int* __restrict__ rowptr,
        float* __restrict__ dis, int* __restrict__ csr) {
    __shared__ int cnt[256];
    __shared__ int lofs[256];
    __shared__ int s[256];
    int b = blockIdx.x;
    int t = threadIdx.x;
    int size  = min(bin_cur[b], BIN_CAP);
    int gbase = bin_base[b];
    const int* bp = binned + (size_t)b * BIN_CAP;
    if (t < 256) cnt[t] = 0;
    __syncthreads();
    int pc[9];                                   // 9*1024 >= BIN_CAP
#pragma unroll
    for (int k = 0; k < 9; ++k) {
        int i = t + k * 1024;
        pc[k] = (i < size) ? __builtin_nontemporal_load(&bp[i]) : -1;
        if (i < size) atomicAdd(&cnt[pc[k] >> SRC_BITS], 1);
    }
    __syncthreads();
    if (t < 256) {
        int n = (b << BSHIFT) + t;
        int deg = cnt[t];
        if (n < N_NODES) dis[n] = 1.0f / sqrtf((float)deg + 1.0f);  // +1 self loop
        s[t] = deg;
    }
    __syncthreads();
    for (int o = 1; o < 256; o <<= 1) {
        int x = 0;
        if (t < 256 && t >= o) x = s[t - o];
        __syncthreads();
        if (t < 256) s[t] += x;
        __syncthreads();
    }
    if (t < 256) {
        int n = (b << BSHIFT) + t;
        int excl = s[t] - cnt[t];
        if (n < N_NODES) rowptr[n] = gbase + excl;
        lofs[t] = excl;
        cnt[t] = 0;
    }
    __syncthreads();
#pragma unroll
    for (int k = 0; k < 9; ++k) {
        int i = t + k * 1024;
        if (i < size) {
            int p = pc[k];
            int ln = p >> SRC_BITS;
            int r = atomicAdd(&cnt[ln], 1);
            csr[gbase + lofs[ln] + r] = p & SRC_MASK;
        }
    }
}

// ================= per-layer kernels =================

__global__ void pre1_kernel(const float* __restrict__ x, const float* __restrict__ dis,
                            float* __restrict__ xs) {
    int i = blockIdx.x * blockDim.x + threadIdx.x;
    if (i >= N_NODES) return;
    float d = dis[i];
    float4 v;
    v.x = __builtin_nontemporal_load(&x[(size_t)i * 3 + 0]) * d;
    v.y = __builtin_nontemporal_load(&x[(size_t)i * 3 + 1]) * d;
    v.z = __builtin_nontemporal_load(&x[(size_t)i * 3 + 2]) * d;
    v.w = 0.f;
    *reinterpret_cast<float4*>(&xs[(size_t)i * 4]) = v;
}

// Row-parallel gather (fp32 operand, layer 1): 16 lanes/node.
template<int F, bool ADD_B, bool RELU>
__global__ __launch_bounds__(256) void gather_kernel(
        const float* __restrict__ in, const int* __restrict__ rowptr,
        const int* __restrict__ csr, const float* __restrict__ dis,
        const float* __restrict__ b, float* __restrict__ out) {
    constexpr int VPL = F / 4;          // features per sublane
    constexpr int NPB = 256 / 16;       // 16 nodes per block
    int tid  = threadIdx.x;
    int sub  = tid & 3;                 // feature sublane
    int qtr  = (tid >> 2) & 3;          // edge-range quarter
    int n    = blockIdx.x * NPB + (tid >> 4);
    if (n >= N_NODES) return;           // never taken: 6250*16 == N exactly
    int beg = rowptr[n], end = rowptr[n + 1];
    int len = end - beg;
    int kb = beg + ((len * qtr) >> 2);
    int ke = beg + ((len * (qtr + 1)) >> 2);
    const float* ip = in + (size_t)sub * VPL;
    float a0[VPL], a1[VPL], a2[VPL], a3[VPL];
#pragma unroll
    for (int j = 0; j < VPL; ++j) { a0[j] = 0.f; a1[j] = 0.f; a2[j] = 0.f; a3[j] = 0.f; }
    if (qtr == 0) {
#pragma unroll
        for (int j = 0; j < VPL; ++j) a0[j] = ip[(size_t)n * F + j];  // self loop
    }
    int k = kb;
    for (; k + 7 < ke; k += 8) {
        int s0 = __builtin_nontemporal_load(&csr[k + 0]);
        int s1 = __builtin_nontemporal_load(&csr[k + 1]);
        int s2 = __builtin_nontemporal_load(&csr[k + 2]);
        int s3 = __builtin_nontemporal_load(&csr[k + 3]);
        int s4 = __builtin_nontemporal_load(&csr[k + 4]);
        int s5 = __builtin_nontemporal_load(&csr[k + 5]);
        int s6 = __builtin_nontemporal_load(&csr[k + 6]);
        int s7 = __builtin_nontemporal_load(&csr[k + 7]);
        const float* r0 = &ip[(size_t)s0 * F];
        const float* r1 = &ip[(size_t)s1 * F];
        const float* r2 = &ip[(size_t)s2 * F];
        const float* r3 = &ip[(size_t)s3 * F];
        const float* r4 = &ip[(size_t)s4 * F];
        const float* r5 = &ip[(size_t)s5 * F];
        const float* r6 = &ip[(size_t)s6 * F];
        const float* r7 = &ip[(size_t)s7 * F];
#pragma unroll
        for (int j = 0; j < VPL; ++j) a0[j] += r0[j];
#pragma unroll
        for (int j = 0; j < VPL; ++j) a1[j] += r1[j];
#pragma unroll
        for (int j = 0; j < VPL; ++j) a2[j] += r2[j];
#pragma unroll
        for (int j = 0; j < VPL; ++j) a3[j] += r3[j];
#pragma unroll
        for (int j = 0; j < VPL; ++j) a0[j] += r4[j];
#pragma unroll
        for (int j = 0; j < VPL; ++j) a1[j] += r5[j];
#pragma unroll
        for (int j = 0; j < VPL; ++j) a2[j] += r6[j];
#pragma unroll
        for (int j = 0; j < VPL; ++j) a3[j] += r7[j];
    }
    if (k + 3 < ke) {
        int s0 = __builtin_nontemporal_load(&csr[k + 0]);
        int s1 = __builtin_nontemporal_load(&csr[k + 1]);
        int s2 = __builtin_nontemporal_load(&csr[k + 2]);
        int s3 = __builtin_nontemporal_load(&csr[k + 3]);
        const float* r0 = &ip[(size_t)s0 * F];
        const float* r1 = &ip[(size_t)s1 * F];
        const float* r2 = &ip[(size_t)s2 * F];
        const float* r3 = &ip[(size_t)s3 * F];
#pragma unroll
        for (int j = 0; j < VPL; ++j) a0[j] += r0[j];
#pragma unroll
        for (int j = 0; j < VPL; ++j) a1[j] += r1[j];
#pragma unroll
        for (int j = 0; j < VPL; ++j) a2[j] += r2[j];
#pragma unroll
        for (int j = 0; j < VPL; ++j) a3[j] += r3[j];
        k += 4;
    }
    for (; k < ke; ++k) {
        int s0 = __builtin_nontemporal_load(&csr[k]);
        const float* r0 = &ip[(size_t)s0 * F];
#pragma unroll
        for (int j = 0; j < VPL; ++j) a0[j] += r0[j];
    }
    float v[VPL];
#pragma unroll
    for (int j = 0; j < VPL; ++j) v[j] = (a0[j] + a1[j]) + (a2[j] + a3[j]);
#pragma unroll
    for (int j = 0; j < VPL; ++j) v[j] += __shfl_xor(v[j], 4);
#pragma unroll
    for (int j = 0; j < VPL; ++j) v[j] += __shfl_xor(v[j], 8);
    if (qtr == 0) {
        float d = dis[n];
#pragma unroll
        for (int j = 0; j < VPL; ++j) {
            float w = v[j] * d;
            if (ADD_B) w += b[sub * VPL + j];
            if (RELU) w = fmaxf(w, 0.f);
            __builtin_nontemporal_store(w, &out[(size_t)n * F + sub * VPL + j]);
        }
    }
}

// Layer-2 gather, fp16 operand (32B rows -> 3.2MB, per-XCD-L2-resident),
// fp32 accumulate, fused W3 epilogue -> fp16 g8. Structure identical to the
// proven single-phase 8-unroll gather.
__global__ __launch_bounds__(256) void gather16w3_kernel(
        const _Float16* __restrict__ in, const int* __restrict__ rowptr,
        const int* __restrict__ csr, const float* __restrict__ dis,
        const float* __restrict__ b2, const float* __restrict__ W3,
        _Float16* __restrict__ g8) {
    __shared__ float w3s[128];                   // transposed: w3s[o*16+f]
    int tid = threadIdx.x;
    if (tid < 128) {
        int f = tid >> 3, o = tid & 7;
        w3s[o * 16 + f] = W3[tid];
    }
    __syncthreads();
    int sub = tid & 3, qtr = (tid >> 2) & 3;
    int n = blockIdx.x * 16 + (tid >> 4);
    int beg = rowptr[n], end = rowptr[n + 1];
    int len = end - beg;
    int kb = beg + ((len * qtr) >> 2);
    int ke = beg + ((len * (qtr + 1)) >> 2);
    const h4t* ip = reinterpret_cast<const h4t*>(in) + sub;   // row stride: 4 h4
    float a0[4], a1[4], a2[4], a3[4];
#pragma unroll
    for (int j = 0; j < 4; ++j) { a0[j] = 0.f; a1[j] = 0.f; a2[j] = 0.f; a3[j] = 0.f; }
    if (qtr == 0) {
        h4t sv = ip[(size_t)n * 4];              // self loop
#pragma unroll
        for (int j = 0; j < 4; ++j) a0[j] = (float)sv[j];
    }
    int k = kb;
    for (; k + 7 < ke; k += 8) {
        int s0 = __builtin_nontemporal_load(&csr[k + 0]);
        int s1 = __builtin_nontemporal_load(&csr[k + 1]);
        int s2 = __builtin_nontemporal_load(&csr[k + 2]);
        int s3 = __builtin_nontemporal_load(&csr[k + 3]);
        int s4 = __builtin_nontemporal_load(&csr[k + 4]);
        int s5 = __builtin_nontemporal_load(&csr[k + 5]);
        int s6 = __builtin_nontemporal_load(&csr[k + 6]);
        int s7 = __builtin_nontemporal_load(&csr[k + 7]);
        h4t v0 = ip[(size_t)s0 * 4];
        h4t v1 = ip[(size_t)s1 * 4];
        h4t v2 = ip[(size_t)s2 * 4];
        h4t v3 = ip[(size_t)s3 * 4];
        h4t v4 = ip[(size_t)s4 * 4];
        h4t v5 = ip[(size_t)s5 * 4];
        h4t v6 = ip[(size_t)s6 * 4];
        h4t v7 = ip[(size_t)s7 * 4];
#pragma unroll
        for (int j = 0; j < 4; ++j) a0[j] += (float)v0[j];
#pragma unroll
        for (int j = 0; j < 4; ++j) a1[j] += (float)v1[j];
#pragma unroll
        for (int j = 0; j < 4; ++j) a2[j] += (float)v2[j];
#pragma unroll
        for (int j = 0; j < 4; ++j) a3[j] += (float)v3[j];
#pragma unroll
        for (int j = 0; j < 4; ++j) a0[j] += (float)v4[j];
#pragma unroll
        for (int j = 0; j < 4; ++j) a1[j] += (float)v5[j];
#pragma unroll
        for (int j = 0; j < 4; ++j) a2[j] += (float)v6[j];
#pragma unroll
        for (int j = 0; j < 4; ++j) a3[j] += (float)v7[j];
    }
    if (k + 3 < ke) {
        int s0 = __builtin_nontemporal_load(&csr[k + 0]);
        int s1 = __builtin_nontemporal_load(&csr[k + 1]);
        int s2 = __builtin_nontemporal_load(&csr[k + 2]);
        int s3 = __builtin_nontemporal_load(&csr[k + 3]);
        h4t v0 = ip[(size_t)s0 * 4];
        h4t v1 = ip[(size_t)s1 * 4];
        h4t v2 = ip[(size_t)s2 * 4];
        h4t v3 = ip[(size_t)s3 * 4];
#pragma unroll
        for (int j = 0; j < 4; ++j) a0[j] += (float)v0[j];
#pragma unroll
        for (int j = 0; j < 4; ++j) a1[j] += (float)v1[j];
#pragma unroll
        for (int j = 0; j < 4; ++j) a2[j] += (float)v2[j];
#pragma unroll
        for (int j = 0; j < 4; ++j) a3[j] += (float)v3[j];
        k += 4;
    }
    for (; k < ke; ++k) {
        int s0 = __builtin_nontemporal_load(&csr[k]);
        h4t v0 = ip[(size_t)s0 * 4];
#pragma unroll
        for (int j = 0; j < 4; ++j) a0[j] += (float)v0[j];
    }
    float d = dis[n];
    float w[4];
#pragma unroll
    for (int j = 0; j < 4; ++j) {
        float v = (a0[j] + a1[j]) + (a2[j] + a3[j]);
        v += __shfl_xor(v, 4);
        v += __shfl_xor(v, 8);                    // all lanes hold full sum
        w[j] = fmaxf(fmaf(v, d, b2[sub * 4 + j]), 0.f);   // h2 slice (relu'd)
    }
    float p[8];
#pragma unroll
    for (int o = 0; o < 8; ++o) {
        float s = 0.f;
#pragma unroll
        for (int j = 0; j < 4; ++j) s = fmaf(w[j], w3s[o * 16 + sub * 4 + j], s);
        s += __shfl_xor(s, 1);
        s += __shfl_xor(s, 2);                    // sum over sublanes
        p[o] = s;
    }
    if (qtr == 0) {
        h2t o2;
        o2[0] = (_Float16)(p[sub * 2 + 0] * d);
        o2[1] = (_Float16)(p[sub * 2 + 1] * d);
        *reinterpret_cast<h2t*>(g8 + (size_t)n * 8 + sub * 2) = o2;  // cached: next gather's operand
    }
}

// Layer-3 gather, fp16 operand (16B rows -> 1.6MB, L2-resident), fp32 accum,
// +b3, relu, fp32 out.
__global__ __launch_bounds__(256) void gather8h_kernel(
        const _Float16* __restrict__ in, const int* __restrict__ rowptr,
        const int* __restrict__ csr, const float* __restrict__ dis,
        const float* __restrict__ b3, float* __restrict__ out) {
    int tid = threadIdx.x;
    int sub = tid & 3, qtr = (tid >> 2) & 3;
    int n = blockIdx.x * 16 + (tid >> 4);
    int beg = rowptr[n], end = rowptr[n + 1];
    int len = end - beg;
    int kb = beg + ((len * qtr) >> 2);
    int ke = beg + ((len * (qtr + 1)) >> 2);
    const h2t* ip = reinterpret_cast<const h2t*>(in) + sub;   // row stride: 4 h2
    float a0[2], a1[2], a2[2], a3[2];
#pragma unroll
    for (int j = 0; j < 2; ++j) { a0[j] = 0.f; a1[j] = 0.f; a2[j] = 0.f; a3[j] = 0.f; }
    if (qtr == 0) {
        h2t sv = ip[(size_t)n * 4];              // self loop
        a0[0] = (float)sv[0]; a0[1] = (float)sv[1];
    }
    int k = kb;
    for (; k + 7 < ke; k += 8) {
        int s0 = __builtin_nontemporal_load(&csr[k + 0]);
        int s1 = __builtin_nontemporal_load(&csr[k + 1]);
        int s2 = __builtin_nontemporal_load(&csr[k + 2]);
        int s3 = __builtin_nontemporal_load(&csr[k + 3]);
        int s4 = __builtin_nontemporal_load(&csr[k + 4]);
        int s5 = __builtin_nontemporal_load(&csr[k + 5]);
        int s6 = __builtin_nontemporal_load(&csr[k + 6]);
        int s7 = __builtin_nontemporal_load(&csr[k + 7]);
        h2t v0 = ip[(size_t)s0 * 4];
        h2t v1 = ip[(size_t)s1 * 4];
        h2t v2 = ip[(size_t)s2 * 4];
        h2t v3 = ip[(size_t)s3 * 4];
        h2t v4 = ip[(size_t)s4 * 4];
        h2t v5 = ip[(size_t)s5 * 4];
        h2t v6 = ip[(size_t)s6 * 4];
        h2t v7 = ip[(size_t)s7 * 4];
        a0[0] += (float)v0[0]; a0[1] += (float)v0[1];
        a1[0] += (float)v1[0]; a1[1] += (float)v1[1];
        a2[0] += (float)v2[0]; a2[1] += (float)v2[1];
        a3[0] += (float)v3[0]; a3[1] += (float)v3[1];
        a0[0] += (float)v4[0]; a0[1] += (float)v4[1];
        a1[0] += (float)v5[0]; a1[1] += (float)v5[1];
        a2[0] += (float)v6[0]; a2[1] += (float)v6[1];
        a3[0] += (float)v7[0]; a3[1] += (float)v7[1];
    }
    if (k + 3 < ke) {
        int s0 = __builtin_nontemporal_load(&csr[k + 0]);
        int s1 = __builtin_nontemporal_load(&csr[k + 1]);
        int s2 = __builtin_nontemporal_load(&csr[k + 2]);
        int s3 = __builtin_nontemporal_load(&csr[k + 3]);
        h2t v0 = ip[(size_t)s0 * 4];
        h2t v1 = ip[(size_t)s1 * 4];
        h2t v2 = ip[(size_t)s2 * 4];
        h2t v3 = ip[(size_t)s3 * 4];
        a0[0] += (float)v0[0]; a0[1] += (float)v0[1];
        a1[0] += (float)v1[0]; a1[1] += (float)v1[1];
        a2[0] += (float)v2[0]; a2[1] += (float)v2[1];
        a3[0] += (float)v3[0]; a3[1] += (float)v3[1];
        k += 4;
    }
    for (; k < ke; ++k) {
        int s0 = __builtin_nontemporal_load(&csr[k]);
        h2t v0 = ip[(size_t)s0 * 4];
        a0[0] += (float)v0[0]; a0[1] += (float)v0[1];
    }
    float v[2];
#pragma unroll
    for (int j = 0; j < 2; ++j) {
        v[j] = (a0[j] + a1[j]) + (a2[j] + a3[j]);
        v[j] += __shfl_xor(v[j], 4);
        v[j] += __shfl_xor(v[j], 8);
    }
    if (qtr == 0) {
        float d = dis[n];
#pragma unroll
        for (int j = 0; j < 2; ++j) {
            float w = fmaxf(fmaf(v[j], d, b3[sub * 2 + j]), 0.f);
            __builtin_nontemporal_store(w, &out[(size_t)n * 8 + sub * 2 + j]);
        }
    }
}

// Fused: m -> relu(m@W1+b1) -> (@W2)*dis -> g (fp16)   (h1 never hits memory)
__global__ __launch_bounds__(256) void linfuse_kernel(
        const float* __restrict__ m, const float* __restrict__ W1,
        const float* __restrict__ b1, const float* __restrict__ W2,
        const float* __restrict__ dis, _Float16* __restrict__ g) {
    __shared__ float w2s[512];
    __shared__ float w1s[96];
    __shared__ float b1s[32];
    int tid = threadIdx.x;
    for (int j = tid; j < 512; j += 256) w2s[j] = W2[j];
    if (tid < 96) w1s[tid] = W1[tid];
    if (tid < 32) b1s[tid] = b1[tid];
    __syncthreads();
    int i = blockIdx.x * blockDim.x + tid;
    if (i >= N_NODES) return;
    float4 mv = *reinterpret_cast<const float4*>(&m[(size_t)i * 4]);
    float h[32];
#pragma unroll
    for (int f = 0; f < 32; ++f) {
        float s = b1s[f];
        s = fmaf(mv.x, w1s[f], s);
        s = fmaf(mv.y, w1s[32 + f], s);
        s = fmaf(mv.z, w1s[64 + f], s);
        h[f] = fmaxf(s, 0.f);
    }
    float d = dis[i];
    h4t* op = reinterpret_cast<h4t*>(g + (size_t)i * 16);
#pragma unroll
    for (int q = 0; q < 4; ++q) {
        h4t v;
#pragma unroll
        for (int jo = 0; jo < 4; ++jo) {
            int o = q * 4 + jo;
            float s = 0.f;
#pragma unroll
            for (int f = 0; f < 32; ++f) s = fmaf(h[f], w2s[f * 16 + o], s);
            v[jo] = (_Float16)(s * d);
        }
        op[q] = v;                               // cached: next gather's operand
    }
}

// ================= pooling + final linear =================

__global__ void pool_kernel(const float* __restrict__ h, const int* __restrict__ batch,
                            float* __restrict__ pool) {
    __shared__ float lsum[N_GRAPHS * 8];
    __shared__ float lcnt[N_GRAPHS];
    int tid = threadIdx.x;
    for (int j = tid; j < N_GRAPHS * 8; j += blockDim.x) lsum[j] = 0.f;
    for (int j = tid; j < N_GRAPHS; j += blockDim.x) lcnt[j] = 0.f;
    __syncthreads();
    int i = blockIdx.x * blockDim.x + tid;
    if (i < N_NODES) {
        int gm = batch[i];
        const float4* hp = reinterpret_cast<const float4*>(&h[(size_t)i * 8]);
        float4 a = hp[0], bq = hp[1];
        atomicAdd(&lsum[gm * 8 + 0], a.x);
        atomicAdd(&lsum[gm * 8 + 1], a.y);
        atomicAdd(&lsum[gm * 8 + 2], a.z);
        atomicAdd(&lsum[gm * 8 + 3], a.w);
        atomicAdd(&lsum[gm * 8 + 4], bq.x);
        atomicAdd(&lsum[gm * 8 + 5], bq.y);
        atomicAdd(&lsum[gm * 8 + 6], bq.z);
        atomicAdd(&lsum[gm * 8 + 7], bq.w);
        atomicAdd(&lcnt[gm], 1.0f);
    }
    __syncthreads();
    for (int idx = tid; idx < N_GRAPHS * 9; idx += blockDim.x) {
        int gm = idx / 9, j = idx % 9;
        if (lcnt[gm] != 0.f) {
            if (j < 8) atomicAdd(&pool[gm * 8 + j], lsum[gm * 8 + j]);
            else       atomicAdd(&pool[512 + gm], lcnt[gm]);
        }
    }
}

__global__ void final_kernel(const float* __restrict__ pool, const float* __restrict__ Wf,
                             const float* __restrict__ bf, float* __restrict__ out) {
    int t = threadIdx.x;
    if (t >= N_GRAPHS * 3) return;
    int gm = t / 3, c = t % 3;
    float cnt = fmaxf(pool[512 + gm], 1.0f);
    float s = 0.f;
#pragma unroll
    for (int f = 0; f < 8; ++f) s = fmaf(pool[gm * 8 + f] / cnt, Wf[f * 3 + c], s);
    out[t] = s + bf[c];
}

// ================= launch =================

extern "C" void kernel_launch(void* const* d_in, const int* in_sizes, int n_in,
                              void* d_out, int out_size, void* d_ws, size_t ws_size,
                              hipStream_t stream) {
    const float* x     = (const float*)d_in[0];
    const int*   ei    = (const int*)d_in[1];
    const int*   batch = (const int*)d_in[2];
    const float* W1 = (const float*)d_in[3];
    const float* b1 = (const float*)d_in[4];
    const float* W2 = (const float*)d_in[5];
    const float* b2 = (const float*)d_in[6];
    const float* W3 = (const float*)d_in[7];
    const float* b3 = (const float*)d_in[8];
    const float* Wf = (const float*)d_in[9];
    const float* bf = (const float*)d_in[10];

    const int* src = ei;              // edge_index[0] = message sources
    const int* dst = ei + N_EDGES;    // edge_index[1] = aggregation targets

    const int N = N_NODES;

    // workspace; binned (36N ints) aliases the activation region (36N floats)
    // act liveness (units of N floats):
    //   L1: xs[0,4) -> m[4,8) -> [linfuse] -> gh[8,16)   (fp16: 16N halves)
    //   L2+W3: gh[8,16) -> g8h[16,20)                     (fp16: 8N halves)
    //   L3: g8h[16,20) -> h3[0,8)  (xs,m dead) -> pool
    int*   bin_cur  = (int*)d_ws;                         // NBINS
    int*   bin_base = bin_cur + NBINS;                    // NBINS
    int*   rowptr   = bin_base + NBINS;                   // N+2
    float* dis      = (float*)(rowptr + N + 2);           // N
    int*   csr      = (int*)(dis + N);                    // E
    float* act      = (float*)(csr + N_EDGES);            // 36N floats
    int*   binned   = (int*)act;                          // 36N ints
    float*    xs   = act;                                 // 4N
    float*    m    = act + (size_t)4  * N;                // 4N
    _Float16* gh   = (_Float16*)(act + (size_t)8  * N);   // 16N halves (= 8N floats)
    _Float16* g8h  = (_Float16*)(act + (size_t)16 * N);   // 8N halves  (= 4N floats)
    float*    h3   = act;                                 // 8N [0,8)
    float*    pool = act + (size_t)36 * N;                // 576

    const int B = 256;
    const int NB_N = (N + B - 1) / B;     // 391
    const int NB_G = N / 16;              // 6250 (exact)

    hipMemsetAsync(bin_cur, 0, NBINS * sizeof(int), stream);
    hipMemsetAsync(pool, 0, N_GRAPHS * 9 * sizeof(float), stream);

    // CSR build
    bin_kernel<<<NB_BIN, 1024, 0, stream>>>(src, dst, bin_cur, binned);
    binscan_kernel<<<1, 512, 0, stream>>>(bin_cur, bin_base, rowptr);
    csrbuild_kernel<<<NBINS, 1024, 0, stream>>>(binned, bin_cur, bin_base, rowptr, dis, csr);

    // Layer 1: aggregate padded 3-dim input, then fused (W1+relu)+(W2·dis) -> fp16 g
    pre1_kernel<<<NB_N, B, 0, stream>>>(x, dis, xs);
    gather_kernel<4, false, false><<<NB_G, B, 0, stream>>>(xs, rowptr, csr, dis, b1, m);
    linfuse_kernel<<<NB_N, B, 0, stream>>>(m, W1, b1, W2, dis, gh);

    // Layer 2: fp16-operand 16-wide gather + fused W3 epilogue -> fp16 g8
    gather16w3_kernel<<<NB_G, B, 0, stream>>>(gh, rowptr, csr, dis, b2, W3, g8h);

    // Layer 3: fp16-operand 8-wide gather (+b3, relu) -> fp32 h3
    gather8h_kernel<<<NB_G, B, 0, stream>>>(g8h, rowptr, csr, dis, b3, h3);

    // Pool + final linear
    pool_kernel<<<NB_N, B, 0, stream>>>(h3, batch, pool);
    final_kernel<<<1, 256, 0, stream>>>(pool, Wf, bf, (float*)d_out);
}

// Round 18
// 175.306 us; speedup vs baseline: 1.1549x; 1.0010x over previous
//
#include <hip/hip_runtime.h>

constexpr int N_NODES  = 100000;
constexpr int N_EDGES  = 3200000;
constexpr int N_GRAPHS = 64;

constexpr int BSHIFT   = 8;                              // 256 nodes per bin
constexpr int NBINS    = (N_NODES + 255) >> BSHIFT;      // 391
constexpr int BIN_CAP  = 9216;                           // mean 8184, +11 sigma
constexpr int SRC_BITS = 17;                             // 100000 < 2^17
constexpr int SRC_MASK = (1 << SRC_BITS) - 1;

constexpr int NB_BIN = 500;                              // ~2 blocks/CU
constexpr int EPB    = N_EDGES / NB_BIN;                 // 6400 (exact)
constexpr int EPT    = (EPB + 1023) / 1024;              // 7

typedef float    v4f __attribute__((ext_vector_type(4)));
typedef _Float16 h2t __attribute__((ext_vector_type(2)));
typedef _Float16 h4t __attribute__((ext_vector_type(4)));

// ================= CSR build: block-local LDS counting sort =================

// Single LDS-atomic pass: rank captured in registers during the histogram.
__global__ __launch_bounds__(1024) void bin_kernel(
        const int* __restrict__ src, const int* __restrict__ dst,
        int* __restrict__ bin_cur, int* __restrict__ binned) {
    __shared__ int pk[EPB];                 // packed (ln<<17)|src, load order
    __shared__ unsigned short bn[EPB];      // bin id, load order
    __shared__ unsigned short ord[EPB];     // sorted pos -> load index
    __shared__ int hist[NBINS];
    __shared__ int lexcl[NBINS];
    __shared__ int gofs[NBINS];
    __shared__ int s512[512];
    int tid = threadIdx.x;
    int e0 = blockIdx.x * EPB;
    for (int i = tid; i < NBINS; i += 1024) hist[i] = 0;
    __syncthreads();
    unsigned short bk[EPT];
    unsigned short rk[EPT];
#pragma unroll
    for (int k = 0; k < EPT; ++k) {
        int i = tid + k * 1024;
        if (i < EPB) {
            int d = __builtin_nontemporal_load(&dst[e0 + i]);
            int s = __builtin_nontemporal_load(&src[e0 + i]);
            int b = d >> BSHIFT;
            pk[i] = ((d & 255) << SRC_BITS) | s;
            bn[i] = (unsigned short)b;
            bk[k] = (unsigned short)b;
            rk[k] = (unsigned short)atomicAdd(&hist[b], 1);   // rank within (block,bin)
        }
    }
    __syncthreads();
    if (tid < 512) s512[tid] = (tid < NBINS) ? hist[tid] : 0;
    __syncthreads();
    for (int o = 1; o < 512; o <<= 1) {
        int x = 0;
        if (tid < 512 && tid >= o) x = s512[tid - o];
        __syncthreads();
        if (tid < 512) s512[tid] += x;
        __syncthreads();
    }
    if (tid < NBINS) {
        int h = hist[tid];
        int excl = s512[tid] - h;
        lexcl[tid] = excl;
        gofs[tid]  = h ? atomicAdd(&bin_cur[tid], h) : 0;
    }
    __syncthreads();
    // build sorted order directly from register ranks (no second atomic pass)
#pragma unroll
    for (int k = 0; k < EPT; ++k) {
        int i = tid + k * 1024;
        if (i < EPB) ord[lexcl[bk[k]] + rk[k]] = (unsigned short)i;
    }
    __syncthreads();
    // coalesced run write-out (NT: consumer is cross-XCD)
#pragma unroll
    for (int k = 0; k < EPT; ++k) {
        int i = tid + k * 1024;
        if (i < EPB) {
            int j = ord[i];
            int b = bn[j];
            int pos = gofs[b] + (i - lexcl[b]);
            if (pos < BIN_CAP)
                __builtin_nontemporal_store(pk[j], &binned[(size_t)b * BIN_CAP + pos]);
        }
    }
}

__global__ void binscan_kernel(const int* __restrict__ bin_cur, int* __restrict__ bin_base,
                               int* __restrict__ rowptr) {
    __shared__ int s[512];
    int t = threadIdx.x;
    int v = (t < NBINS) ? bin_cur[t] : 0;
    s[t] = v;
    __syncthreads();
    for (int o = 1; o < 512; o <<= 1) {
        int x = (t >= o) ? s[t - o] : 0;
        __syncthreads();
        s[t] += x;
        __syncthreads();
    }
    if (t < NBINS) bin_base[t] = s[t] - v;
    if (t == 0) rowptr[N_NODES] = N_EDGES;
}

__global__ __launch_bounds__(1024) void csrbuild_kernel(
        const int* __restrict__ binned, const int* __restrict__ bin_cur,
        const int* __restrict__ bin_base, int* __restrict__ rowptr,
        float* __restrict__ dis, int* __restrict__ csr) {
    __shared__ int cnt[256];
    __shared__ int lofs[256];
    __shared__ int s[256];
    int b = blockIdx.x;
    int t = threadIdx.x;
    int size  = min(bin_cur[b], BIN_CAP);
    int gbase = bin_base[b];
    const int* bp = binned + (size_t)b * BIN_CAP;
    if (t < 256) cnt[t] = 0;
    __syncthreads();
    int pc[9];                                   // 9*1024 >= BIN_CAP
#pragma unroll
    for (int k = 0; k < 9; ++k) {
        int i = t + k * 1024;
        pc[k] = (i < size) ? __builtin_nontemporal_load(&bp[i]) : -1;
        if (i < size) atomicAdd(&cnt[pc[k] >> SRC_BITS], 1);
    }
    __syncthreads();
    if (t < 256) {
        int n = (b << BSHIFT) + t;
        int deg = cnt[t];
        if (n < N_NODES) dis[n] = 1.0f / sqrtf((float)deg + 1.0f);  // +1 self loop
        s[t] = deg;
    }
    __syncthreads();
    for (int o = 1; o < 256; o <<= 1) {
        int x = 0;
        if (t < 256 && t >= o) x = s[t - o];
        __syncthreads();
        if (t < 256) s[t] += x;
        __syncthreads();
    }
    if (t < 256) {
        int n = (b << BSHIFT) + t;
        int excl = s[t] - cnt[t];
        if (n < N_NODES) rowptr[n] = gbase + excl;
        lofs[t] = excl;
        cnt[t] = 0;
    }
    __syncthreads();
#pragma unroll
    for (int k = 0; k < 9; ++k) {
        int i = t + k * 1024;
        if (i < size) {
            int p = pc[k];
            int ln = p >> SRC_BITS;
            int r = atomicAdd(&cnt[ln], 1);
            csr[gbase + lofs[ln] + r] = p & SRC_MASK;
        }
    }
}

// ================= per-layer kernels =================

__global__ void pre1_kernel(const float* __restrict__ x, const float* __restrict__ dis,
                            float* __restrict__ xs) {
    int i = blockIdx.x * blockDim.x + threadIdx.x;
    if (i >= N_NODES) return;
    float d = dis[i];
    float4 v;
    v.x = __builtin_nontemporal_load(&x[(size_t)i * 3 + 0]) * d;
    v.y = __builtin_nontemporal_load(&x[(size_t)i * 3 + 1]) * d;
    v.z = __builtin_nontemporal_load(&x[(size_t)i * 3 + 2]) * d;
    v.w = 0.f;
    *reinterpret_cast<float4*>(&xs[(size_t)i * 4]) = v;
}

// Row-parallel gather (fp32 operand, layer 1): 16 lanes/node.
template<int F, bool ADD_B, bool RELU>
__global__ __launch_bounds__(256) void gather_kernel(
        const float* __restrict__ in, const int* __restrict__ rowptr,
        const int* __restrict__ csr, const float* __restrict__ dis,
        const float* __restrict__ b, float* __restrict__ out) {
    constexpr int VPL = F / 4;          // features per sublane
    constexpr int NPB = 256 / 16;       // 16 nodes per block
    int tid  = threadIdx.x;
    int sub  = tid & 3;                 // feature sublane
    int qtr  = (tid >> 2) & 3;          // edge-range quarter
    int n    = blockIdx.x * NPB + (tid >> 4);
    if (n >= N_NODES) return;           // never taken: 6250*16 == N exactly
    int beg = rowptr[n], end = rowptr[n + 1];
    int len = end - beg;
    int kb = beg + ((len * qtr) >> 2);
    int ke = beg + ((len * (qtr + 1)) >> 2);
    const float* ip = in + (size_t)sub * VPL;
    float a0[VPL], a1[VPL], a2[VPL], a3[VPL];
#pragma unroll
    for (int j = 0; j < VPL; ++j) { a0[j] = 0.f; a1[j] = 0.f; a2[j] = 0.f; a3[j] = 0.f; }
    if (qtr == 0) {
#pragma unroll
        for (int j = 0; j < VPL; ++j) a0[j] = ip[(size_t)n * F + j];  // self loop
    }
    int k = kb;
    for (; k + 7 < ke; k += 8) {
        int s0 = __builtin_nontemporal_load(&csr[k + 0]);
        int s1 = __builtin_nontemporal_load(&csr[k + 1]);
        int s2 = __builtin_nontemporal_load(&csr[k + 2]);
        int s3 = __builtin_nontemporal_load(&csr[k + 3]);
        int s4 = __builtin_nontemporal_load(&csr[k + 4]);
        int s5 = __builtin_nontemporal_load(&csr[k + 5]);
        int s6 = __builtin_nontemporal_load(&csr[k + 6]);
        int s7 = __builtin_nontemporal_load(&csr[k + 7]);
        const float* r0 = &ip[(size_t)s0 * F];
        const float* r1 = &ip[(size_t)s1 * F];
        const float* r2 = &ip[(size_t)s2 * F];
        const float* r3 = &ip[(size_t)s3 * F];
        const float* r4 = &ip[(size_t)s4 * F];
        const float* r5 = &ip[(size_t)s5 * F];
        const float* r6 = &ip[(size_t)s6 * F];
        const float* r7 = &ip[(size_t)s7 * F];
#pragma unroll
        for (int j = 0; j < VPL; ++j) a0[j] += r0[j];
#pragma unroll
        for (int j = 0; j < VPL; ++j) a1[j] += r1[j];
#pragma unroll
        for (int j = 0; j < VPL; ++j) a2[j] += r2[j];
#pragma unroll
        for (int j = 0; j < VPL; ++j) a3[j] += r3[j];
#pragma unroll
        for (int j = 0; j < VPL; ++j) a0[j] += r4[j];
#pragma unroll
        for (int j = 0; j < VPL; ++j) a1[j] += r5[j];
#pragma unroll
        for (int j = 0; j < VPL; ++j) a2[j] += r6[j];
#pragma unroll
        for (int j = 0; j < VPL; ++j) a3[j] += r7[j];
    }
    if (k + 3 < ke) {
        int s0 = __builtin_nontemporal_load(&csr[k + 0]);
        int s1 = __builtin_nontemporal_load(&csr[k + 1]);
        int s2 = __builtin_nontemporal_load(&csr[k + 2]);
        int s3 = __builtin_nontemporal_load(&csr[k + 3]);
        const float* r0 = &ip[(size_t)s0 * F];
        const float* r1 = &ip[(size_t)s1 * F];
        const float* r2 = &ip[(size_t)s2 * F];
        const float* r3 = &ip[(size_t)s3 * F];
#pragma unroll
        for (int j = 0; j < VPL; ++j) a0[j] += r0[j];
#pragma unroll
        for (int j = 0; j < VPL; ++j) a1[j] += r1[j];
#pragma unroll
        for (int j = 0; j < VPL; ++j) a2[j] += r2[j];
#pragma unroll
        for (int j = 0; j < VPL; ++j) a3[j] += r3[j];
        k += 4;
    }
    for (; k < ke; ++k) {
        int s0 = __builtin_nontemporal_load(&csr[k]);
        const float* r0 = &ip[(size_t)s0 * F];
#pragma unroll
        for (int j = 0; j < VPL; ++j) a0[j] += r0[j];
    }
    float v[VPL];
#pragma unroll
    for (int j = 0; j < VPL; ++j) v[j] = (a0[j] + a1[j]) + (a2[j] + a3[j]);
#pragma unroll
    for (int j = 0; j < VPL; ++j) v[j] += __shfl_xor(v[j], 4);
#pragma unroll
    for (int j = 0; j < VPL; ++j) v[j] += __shfl_xor(v[j], 8);
    if (qtr == 0) {
        float d = dis[n];
#pragma unroll
        for (int j = 0; j < VPL; ++j) {
            float w = v[j] * d;
            if (ADD_B) w += b[sub * VPL + j];
            if (RELU) w = fmaxf(w, 0.f);
            __builtin_nontemporal_store(w, &out[(size_t)n * F + sub * VPL + j]);
        }
    }
}

// Layer-2 gather, fp16 operand (32B rows -> 3.2MB, per-XCD-L2-resident),
// fp32 accumulate, fused W3 epilogue -> fp16 g8.
__global__ __launch_bounds__(256) void gather16w3_kernel(
        const _Float16* __restrict__ in, const int* __restrict__ rowptr,
        const int* __restrict__ csr, const float* __restrict__ dis,
        const float* __restrict__ b2, const float* __restrict__ W3,
        _Float16* __restrict__ g8) {
    __shared__ float w3s[128];                   // transposed: w3s[o*16+f]
    int tid = threadIdx.x;
    if (tid < 128) {
        int f = tid >> 3, o = tid & 7;
        w3s[o * 16 + f] = W3[tid];
    }
    __syncthreads();
    int sub = tid & 3, qtr = (tid >> 2) & 3;
    int n = blockIdx.x * 16 + (tid >> 4);
    int beg = rowptr[n], end = rowptr[n + 1];
    int len = end - beg;
    int kb = beg + ((len * qtr) >> 2);
    int ke = beg + ((len * (qtr + 1)) >> 2);
    const h4t* ip = reinterpret_cast<const h4t*>(in) + sub;   // row stride: 4 h4
    float a0[4], a1[4], a2[4], a3[4];
#pragma unroll
    for (int j = 0; j < 4; ++j) { a0[j] = 0.f; a1[j] = 0.f; a2[j] = 0.f; a3[j] = 0.f; }
    if (qtr == 0) {
        h4t sv = ip[(size_t)n * 4];              // self loop
#pragma unroll
        for (int j = 0; j < 4; ++j) a0[j] = (float)sv[j];
    }
    int k = kb;
    for (; k + 7 < ke; k += 8) {
        int s0 = __builtin_nontemporal_load(&csr[k + 0]);
        int s1 = __builtin_nontemporal_load(&csr[k + 1]);
        int s2 = __builtin_nontemporal_load(&csr[k + 2]);
        int s3 = __builtin_nontemporal_load(&csr[k + 3]);
        int s4 = __builtin_nontemporal_load(&csr[k + 4]);
        int s5 = __builtin_nontemporal_load(&csr[k + 5]);
        int s6 = __builtin_nontemporal_load(&csr[k + 6]);
        int s7 = __builtin_nontemporal_load(&csr[k + 7]);
        h4t v0 = ip[(size_t)s0 * 4];
        h4t v1 = ip[(size_t)s1 * 4];
        h4t v2 = ip[(size_t)s2 * 4];
        h4t v3 = ip[(size_t)s3 * 4];
        h4t v4 = ip[(size_t)s4 * 4];
        h4t v5 = ip[(size_t)s5 * 4];
        h4t v6 = ip[(size_t)s6 * 4];
        h4t v7 = ip[(size_t)s7 * 4];
#pragma unroll
        for (int j = 0; j < 4; ++j) a0[j] += (float)v0[j];
#pragma unroll
        for (int j = 0; j < 4; ++j) a1[j] += (float)v1[j];
#pragma unroll
        for (int j = 0; j < 4; ++j) a2[j] += (float)v2[j];
#pragma unroll
        for (int j = 0; j < 4; ++j) a3[j] += (float)v3[j];
#pragma unroll
        for (int j = 0; j < 4; ++j) a0[j] += (float)v4[j];
#pragma unroll
        for (int j = 0; j < 4; ++j) a1[j] += (float)v5[j];
#pragma unroll
        for (int j = 0; j < 4; ++j) a2[j] += (float)v6[j];
#pragma unroll
        for (int j = 0; j < 4; ++j) a3[j] += (float)v7[j];
    }
    if (k + 3 < ke) {
        int s0 = __builtin_nontemporal_load(&csr[k + 0]);
        int s1 = __builtin_nontemporal_load(&csr[k + 1]);
        int s2 = __builtin_nontemporal_load(&csr[k + 2]);
        int s3 = __builtin_nontemporal_load(&csr[k + 3]);
        h4t v0 = ip[(size_t)s0 * 4];
        h4t v1 = ip[(size_t)s1 * 4];
        h4t v2 = ip[(size_t)s2 * 4];
        h4t v3 = ip[(size_t)s3 * 4];
#pragma unroll
        for (int j = 0; j < 4; ++j) a0[j] += (float)v0[j];
#pragma unroll
        for (int j = 0; j < 4; ++j) a1[j] += (float)v1[j];
#pragma unroll
        for (int j = 0; j < 4; ++j) a2[j] += (float)v2[j];
#pragma unroll
        for (int j = 0; j < 4; ++j) a3[j] += (float)v3[j];
        k += 4;
    }
    for (; k < ke; ++k) {
        int s0 = __builtin_nontemporal_load(&csr[k]);
        h4t v0 = ip[(size_t)s0 * 4];
#pragma unroll
        for (int j = 0; j < 4; ++j) a0[j] += (float)v0[j];
    }
    float d = dis[n];
    float w[4];
#pragma unroll
    for (int j = 0; j < 4; ++j) {
        float v = (a0[j] + a1[j]) + (a2[j] + a3[j]);
        v += __shfl_xor(v, 4);
        v += __shfl_xor(v, 8);                    // all lanes hold full sum
        w[j] = fmaxf(fmaf(v, d, b2[sub * 4 + j]), 0.f);   // h2 slice (relu'd)
    }
    float p[8];
#pragma unroll
    for (int o = 0; o < 8; ++o) {
        float s = 0.f;
#pragma unroll
        for (int j = 0; j < 4; ++j) s = fmaf(w[j], w3s[o * 16 + sub * 4 + j], s);
        s += __shfl_xor(s, 1);
        s += __shfl_xor(s, 2);                    // sum over sublanes
        p[o] = s;
    }
    if (qtr == 0) {
        h2t o2;
        o2[0] = (_Float16)(p[sub * 2 + 0] * d);
        o2[1] = (_Float16)(p[sub * 2 + 1] * d);
        *reinterpret_cast<h2t*>(g8 + (size_t)n * 8 + sub * 2) = o2;  // cached: next gather's operand
    }
}

// Layer-3 gather, fp16 operand (16B rows -> 1.6MB, L2-resident), fp32 accum,
// +b3, relu, fp32 out.
__global__ __launch_bounds__(256) void gather8h_kernel(
        const _Float16* __restrict__ in, const int* __restrict__ rowptr,
        const int* __restrict__ csr, const float* __restrict__ dis,
        const float* __restrict__ b3, float* __restrict__ out) {
    int tid = threadIdx.x;
    int sub = tid & 3, qtr = (tid >> 2) & 3;
    int n = blockIdx.x * 16 + (tid >> 4);
    int beg = rowptr[n], end = rowptr[n + 1];
    int len = end - beg;
    int kb = beg + ((len * qtr) >> 2);
    int ke = beg + ((len * (qtr + 1)) >> 2);
    const h2t* ip = reinterpret_cast<const h2t*>(in) + sub;   // row stride: 4 h2
    float a0[2], a1[2], a2[2], a3[2];
#pragma unroll
    for (int j = 0; j < 2; ++j) { a0[j] = 0.f; a1[j] = 0.f; a2[j] = 0.f; a3[j] = 0.f; }
    if (qtr == 0) {
        h2t sv = ip[(size_t)n * 4];              // self loop
        a0[0] = (float)sv[0]; a0[1] = (float)sv[1];
    }
    int k = kb;
    for (; k + 7 < ke; k += 8) {
        int s0 = __builtin_nontemporal_load(&csr[k + 0]);
        int s1 = __builtin_nontemporal_load(&csr[k + 1]);
        int s2 = __builtin_nontemporal_load(&csr[k + 2]);
        int s3 = __builtin_nontemporal_load(&csr[k + 3]);
        int s4 = __builtin_nontemporal_load(&csr[k + 4]);
        int s5 = __builtin_nontemporal_load(&csr[k + 5]);
        int s6 = __builtin_nontemporal_load(&csr[k + 6]);
        int s7 = __builtin_nontemporal_load(&csr[k + 7]);
        h2t v0 = ip[(size_t)s0 * 4];
        h2t v1 = ip[(size_t)s1 * 4];
        h2t v2 = ip[(size_t)s2 * 4];
        h2t v3 = ip[(size_t)s3 * 4];
        h2t v4 = ip[(size_t)s4 * 4];
        h2t v5 = ip[(size_t)s5 * 4];
        h2t v6 = ip[(size_t)s6 * 4];
        h2t v7 = ip[(size_t)s7 * 4];
        a0[0] += (float)v0[0]; a0[1] += (float)v0[1];
        a1[0] += (float)v1[0]; a1[1] += (float)v1[1];
        a2[0] += (float)v2[0]; a2[1] += (float)v2[1];
        a3[0] += (float)v3[0]; a3[1] += (float)v3[1];
        a0[0] += (float)v4[0]; a0[1] += (float)v4[1];
        a1[0] += (float)v5[0]; a1[1] += (float)v5[1];
        a2[0] += (float)v6[0]; a2[1] += (float)v6[1];
        a3[0] += (float)v7[0]; a3[1] += (float)v7[1];
    }
    if (k + 3 < ke) {
        int s0 = __builtin_nontemporal_load(&csr[k + 0]);
        int s1 = __builtin_nontemporal_load(&csr[k + 1]);
        int s2 = __builtin_nontemporal_load(&csr[k + 2]);
        int s3 = __builtin_nontemporal_load(&csr[k + 3]);
        h2t v0 = ip[(size_t)s0 * 4];
        h2t v1 = ip[(size_t)s1 * 4];
        h2t v2 = ip[(size_t)s2 * 4];
        h2t v3 = ip[(size_t)s3 * 4];
        a0[0] += (float)v0[0]; a0[1] += (float)v0[1];
        a1[0] += (float)v1[0]; a1[1] += (float)v1[1];
        a2[0] += (float)v2[0]; a2[1] += (float)v2[1];
        a3[0] += (float)v3[0]; a3[1] += (float)v3[1];
        k += 4;
    }
    for (; k < ke; ++k) {
        int s0 = __builtin_nontemporal_load(&csr[k]);
        h2t v0 = ip[(size_t)s0 * 4];
        a0[0] += (float)v0[0]; a0[1] += (float)v0[1];
    }
    float v[2];
#pragma unroll
    for (int j = 0; j < 2; ++j) {
        v[j] = (a0[j] + a1[j]) + (a2[j] + a3[j]);
        v[j] += __shfl_xor(v[j], 4);
        v[j] += __shfl_xor(v[j], 8);
    }
    if (qtr == 0) {
        float d = dis[n];
#pragma unroll
        for (int j = 0; j < 2; ++j) {
            float w = fmaxf(fmaf(v[j], d, b3[sub * 2 + j]), 0.f);
            __builtin_nontemporal_store(w, &out[(size_t)n * 8 + sub * 2 + j]);
        }
    }
}

// Fused: m -> relu(m@W1+b1) -> (@W2)*dis -> g (fp16)   (h1 never hits memory)
__global__ __launch_bounds__(256) void linfuse_kernel(
        const float* __restrict__ m, const float* __restrict__ W1,
        const float* __restrict__ b1, const float* __restrict__ W2,
        const float* __restrict__ dis, _Float16* __restrict__ g) {
    __shared__ float w2s[512];
    __shared__ float w1s[96];
    __shared__ float b1s[32];
    int tid = threadIdx.x;
    for (int j = tid; j < 512; j += 256) w2s[j] = W2[j];
    if (tid < 96) w1s[tid] = W1[tid];
    if (tid < 32) b1s[tid] = b1[tid];
    __syncthreads();
    int i = blockIdx.x * blockDim.x + tid;
    if (i >= N_NODES) return;
    float4 mv = *reinterpret_cast<const float4*>(&m[(size_t)i * 4]);
    float h[32];
#pragma unroll
    for (int f = 0; f < 32; ++f) {
        float s = b1s[f];
        s = fmaf(mv.x, w1s[f], s);
        s = fmaf(mv.y, w1s[32 + f], s);
        s = fmaf(mv.z, w1s[64 + f], s);
        h[f] = fmaxf(s, 0.f);
    }
    float d = dis[i];
    h4t* op = reinterpret_cast<h4t*>(g + (size_t)i * 16);
#pragma unroll
    for (int q = 0; q < 4; ++q) {
        h4t v;
#pragma unroll
        for (int jo = 0; jo < 4; ++jo) {
            int o = q * 4 + jo;
            float s = 0.f;
#pragma unroll
            for (int f = 0; f < 32; ++f) s = fmaf(h[f], w2s[f * 16 + o], s);
            v[jo] = (_Float16)(s * d);
        }
        op[q] = v;                               // cached: next gather's operand
    }
}

// ================= pooling + final linear =================

__global__ void pool_kernel(const float* __restrict__ h, const int* __restrict__ batch,
                            float* __restrict__ pool) {
    __shared__ float lsum[N_GRAPHS * 8];
    __shared__ float lcnt[N_GRAPHS];
    int tid = threadIdx.x;
    for (int j = tid; j < N_GRAPHS * 8; j += blockDim.x) lsum[j] = 0.f;
    for (int j = tid; j < N_GRAPHS; j += blockDim.x) lcnt[j] = 0.f;
    __syncthreads();
    int i = blockIdx.x * blockDim.x + tid;
    if (i < N_NODES) {
        int gm = batch[i];
        const float4* hp = reinterpret_cast<const float4*>(&h[(size_t)i * 8]);
        float4 a = hp[0], bq = hp[1];
        atomicAdd(&lsum[gm * 8 + 0], a.x);
        atomicAdd(&lsum[gm * 8 + 1], a.y);
        atomicAdd(&lsum[gm * 8 + 2], a.z);
        atomicAdd(&lsum[gm * 8 + 3], a.w);
        atomicAdd(&lsum[gm * 8 + 4], bq.x);
        atomicAdd(&lsum[gm * 8 + 5], bq.y);
        atomicAdd(&lsum[gm * 8 + 6], bq.z);
        atomicAdd(&lsum[gm * 8 + 7], bq.w);
        atomicAdd(&lcnt[gm], 1.0f);
    }
    __syncthreads();
    for (int idx = tid; idx < N_GRAPHS * 9; idx += blockDim.x) {
        int gm = idx / 9, j = idx % 9;
        if (lcnt[gm] != 0.f) {
            if (j < 8) atomicAdd(&pool[gm * 8 + j], lsum[gm * 8 + j]);
            else       atomicAdd(&pool[512 + gm], lcnt[gm]);
        }
    }
}

__global__ void final_kernel(const float* __restrict__ pool, const float* __restrict__ Wf,
                             const float* __restrict__ bf, float* __restrict__ out) {
    int t = threadIdx.x;
    if (t >= N_GRAPHS * 3) return;
    int gm = t / 3, c = t % 3;
    float cnt = fmaxf(pool[512 + gm], 1.0f);
    float s = 0.f;
#pragma unroll
    for (int f = 0; f < 8; ++f) s = fmaf(pool[gm * 8 + f] / cnt, Wf[f * 3 + c], s);
    out[t] = s + bf[c];
}

// ================= launch =================

extern "C" void kernel_launch(void* const* d_in, const int* in_sizes, int n_in,
                              void* d_out, int out_size, void* d_ws, size_t ws_size,
                              hipStream_t stream) {
    const float* x     = (const float*)d_in[0];
    const int*   ei    = (const int*)d_in[1];
    const int*   batch = (const int*)d_in[2];
    const float* W1 = (const float*)d_in[3];
    const float* b1 = (const float*)d_in[4];
    const float* W2 = (const float*)d_in[5];
    const float* b2 = (const float*)d_in[6];
    const float* W3 = (const float*)d_in[7];
    const float* b3 = (const float*)d_in[8];
    const float* Wf = (const float*)d_in[9];
    const float* bf = (const float*)d_in[10];

    const int* src = ei;              // edge_index[0] = message sources
    const int* dst = ei + N_EDGES;    // edge_index[1] = aggregation targets

    const int N = N_NODES;

    // workspace; binned (36N ints) aliases the activation region (36N floats)
    // act liveness (units of N floats):
    //   L1: xs[0,4) -> m[4,8) -> [linfuse] -> gh[8,16)   (fp16: 16N halves)
    //   L2+W3: gh[8,16) -> g8h[16,20)                     (fp16: 8N halves)
    //   L3: g8h[16,20) -> h3[0,8)  (xs,m dead) -> pool
    int*   bin_cur  = (int*)d_ws;                         // NBINS
    int*   bin_base = bin_cur + NBINS;                    // NBINS
    int*   rowptr   = bin_base + NBINS;                   // N+2
    float* dis      = (float*)(rowptr + N + 2);           // N
    int*   csr      = (int*)(dis + N);                    // E
    float* act      = (float*)(csr + N_EDGES);            // 36N floats
    int*   binned   = (int*)act;                          // 36N ints
    float*    xs   = act;                                 // 4N
    float*    m    = act + (size_t)4  * N;                // 4N
    _Float16* gh   = (_Float16*)(act + (size_t)8  * N);   // 16N halves (= 8N floats)
    _Float16* g8h  = (_Float16*)(act + (size_t)16 * N);   // 8N halves  (= 4N floats)
    float*    h3   = act;                                 // 8N [0,8)
    float*    pool = act + (size_t)36 * N;                // 576

    const int B = 256;
    const int NB_N = (N + B - 1) / B;     // 391
    const int NB_G = N / 16;              // 6250 (exact)

    hipMemsetAsync(bin_cur, 0, NBINS * sizeof(int), stream);
    hipMemsetAsync(pool, 0, N_GRAPHS * 9 * sizeof(float), stream);

    // CSR build
    bin_kernel<<<NB_BIN, 1024, 0, stream>>>(src, dst, bin_cur, binned);
    binscan_kernel<<<1, 512, 0, stream>>>(bin_cur, bin_base, rowptr);
    csrbuild_kernel<<<NBINS, 1024, 0, stream>>>(binned, bin_cur, bin_base, rowptr, dis, csr);

    // Layer 1: aggregate padded 3-dim input, then fused (W1+relu)+(W2·dis) -> fp16 g
    pre1_kernel<<<NB_N, B, 0, stream>>>(x, dis, xs);
    gather_kernel<4, false, false><<<NB_G, B, 0, stream>>>(xs, rowptr, csr, dis, b1, m);
    linfuse_kernel<<<NB_N, B, 0, stream>>>(m, W1, b1, W2, dis, gh);

    // Layer 2: fp16-operand 16-wide gather + fused W3 epilogue -> fp16 g8
    gather16w3_kernel<<<NB_G, B, 0, stream>>>(gh, rowptr, csr, dis, b2, W3, g8h);

    // Layer 3: fp16-operand 8-wide gather (+b3, relu) -> fp32 h3
    gather8h_kernel<<<NB_G, B, 0, stream>>>(g8h, rowptr, csr, dis, b3, h3);

    // Pool + final linear
    pool_kernel<<<NB_N, B, 0, stream>>>(h3, batch, pool);
    final_kernel<<<1, 256, 0, stream>>>(pool, Wf, bf, (float*)d_out);
}